// Round 6
// baseline (384.902 us; speedup 1.0000x reference)
//
#include <hip/hip_runtime.h>
#include <hip/hip_bf16.h>
#include <math.h>

#define B_ 4
#define S_ 1024
#define D_ 1024
#define H_ 16
#define HD_ 64

typedef __hip_bfloat16 bf16_t;
typedef __attribute__((ext_vector_type(8))) short bf16x8;
typedef __attribute__((ext_vector_type(4))) float floatx4;

__device__ __forceinline__ float bf2f(ushort u) {
  return __uint_as_float((unsigned)u << 16);
}

// ---- prep: one launch = LN1 (4096 row-blocks) + all 6 weight transposes ----
__global__ __launch_bounds__(256) void prep_kernel(
    const float* __restrict__ x, const float* __restrict__ ln1s,
    const float* __restrict__ ln1b, bf16_t* __restrict__ h,
    const float* __restrict__ wq, const float* __restrict__ wk,
    const float* __restrict__ wv, const float* __restrict__ wo,
    const float* __restrict__ w1, const float* __restrict__ w2,
    bf16_t* __restrict__ wqkv_t, bf16_t* __restrict__ wo_t,
    bf16_t* __restrict__ w1_t, bf16_t* __restrict__ w2_t) {
  const int id = blockIdx.x;
  if (id < 4096) {  // ---- LayerNorm row ----
    const int row = id;
    float4 v = ((const float4*)(x + (size_t)row * D_))[threadIdx.x];
    float s = v.x + v.y + v.z + v.w;
    float ss = v.x * v.x + v.y * v.y + v.z * v.z + v.w * v.w;
#pragma unroll
    for (int off = 32; off > 0; off >>= 1) {
      s += __shfl_xor(s, off);
      ss += __shfl_xor(ss, off);
    }
    __shared__ float ls[4], lss[4], stats[2];
    const int wave = threadIdx.x >> 6, lane = threadIdx.x & 63;
    if (lane == 0) { ls[wave] = s; lss[wave] = ss; }
    __syncthreads();
    if (threadIdx.x == 0) {
      float t = ls[0] + ls[1] + ls[2] + ls[3];
      float tt = lss[0] + lss[1] + lss[2] + lss[3];
      float mean = t * (1.0f / D_);
      stats[0] = mean;
      stats[1] = rsqrtf(tt * (1.0f / D_) - mean * mean + 1e-5f);
    }
    __syncthreads();
    const float mean = stats[0], rstd = stats[1];
    float4 sc = ((const float4*)ln1s)[threadIdx.x];
    float4 sh = ((const float4*)ln1b)[threadIdx.x];
    bf16_t ob[4];
    ob[0] = __float2bfloat16(sc.x * (v.x - mean) * rstd + sh.x);
    ob[1] = __float2bfloat16(sc.y * (v.y - mean) * rstd + sh.y);
    ob[2] = __float2bfloat16(sc.z * (v.z - mean) * rstd + sh.z);
    ob[3] = __float2bfloat16(sc.w * (v.w - mean) * rstd + sh.w);
    *(ushort4*)(h + (size_t)row * D_ + threadIdx.x * 4) = *(ushort4*)ob;
    return;
  }
  const float* W;
  bf16_t* Wt;
  int K, N, n0, k0;
  if (id < 8192) {
    const int t = id - 4096, which = t >> 10, tile = t & 1023;
    n0 = (tile & 31) * 32;
    k0 = (tile >> 5) * 32;
    K = 1024; N = 1024;
    W = which == 0 ? wq : which == 1 ? wk : which == 2 ? wv : wo;
    Wt = which < 3 ? wqkv_t + (size_t)which * 1024 * 1024 : wo_t;
  } else if (id < 12288) {
    const int tile = id - 8192;
    n0 = (tile & 127) * 32;
    k0 = (tile >> 7) * 32;
    K = 1024; N = 4096;
    W = w1; Wt = w1_t;
  } else {
    const int tile = id - 12288;
    n0 = (tile & 31) * 32;
    k0 = (tile >> 5) * 32;
    K = 4096; N = 1024;
    W = w2; Wt = w2_t;
  }
  __shared__ float t[32][33];
  const int lx = threadIdx.x & 31, ly = threadIdx.x >> 5;  // 32 x 8
#pragma unroll
  for (int r = ly; r < 32; r += 8) t[r][lx] = W[(size_t)(k0 + r) * N + n0 + lx];
  __syncthreads();
#pragma unroll
  for (int r = ly; r < 32; r += 8)
    Wt[(size_t)(n0 + r) * K + k0 + lx] = __float2bfloat16(t[lx][r]);
}

// ------------- bf16 MFMA GEMM body: 128x128 tile, BK=64, XCD-clustered ------
// mode 0: C bf16 | 1: bias+gelu -> C bf16 | 4: bf16 partial + z*M*N (split-K)
// mode 5: fp32 residual RMW  C[row][col] += bias[col] + gemm  (fused ffn2)
__device__ __forceinline__ void mgemm_body(
    const bf16_t* __restrict__ A, const bf16_t* __restrict__ Bt,
    const float* __restrict__ bias, void* __restrict__ C, int M, int N, int K,
    int Kc, int Mt, int Nt, int PM, int mode, int flat, bf16_t* As,
    bf16_t* Bs) {
  const int tid = threadIdx.x;
  const int lane = tid & 63, w = tid >> 6;

  // --- XCD-cluster decode ---
  const int xcd = flat & 7;
  int t0 = flat >> 3;
  const int mb = xcd % PM, nb = xcd / PM;
  const int mt = mb * Mt + (t0 % Mt);
  t0 /= Mt;
  const int nt = nb * Nt + (t0 % Nt);
  const int z = t0 / Nt;
  const int m0 = mt * 128, n0 = nt * 128;
  const int kz0 = z * Kc;
  const int wm = (w >> 1) * 64, wn = (w & 1) * 64;

  floatx4 zero = {0.f, 0.f, 0.f, 0.f};
  floatx4 acc[4][4];
#pragma unroll
  for (int i = 0; i < 4; i++)
#pragma unroll
    for (int j = 0; j < 4; j++) acc[i][j] = zero;

  // staging: chunk c (1KB = 8 rows x 128B) handled by wave c&3, c = w+4t.
  const int ro8 = lane >> 3;                 // row within chunk
  const int g8 = ((lane & 7) ^ ro8) * 8;     // swizzled source col (elements)
  const bf16_t* ga[4];
  const bf16_t* gb[4];
  bf16_t* la[4];
  bf16_t* lb[4];
#pragma unroll
  for (int t = 0; t < 4; t++) {
    const int c = w + 4 * t;
    ga[t] = A + (size_t)(m0 + c * 8 + ro8) * K + g8;
    gb[t] = Bt + (size_t)(n0 + c * 8 + ro8) * K + g8;
    la[t] = &As[c * 512];
    lb[t] = &Bs[c * 512];
  }

  const int fr = lane & 15, quad = lane >> 4;

  for (int k0 = kz0; k0 < kz0 + Kc; k0 += 64) {
    __syncthreads();
#pragma unroll
    for (int t = 0; t < 4; t++) {
      __builtin_amdgcn_global_load_lds(
          (const __attribute__((address_space(1))) void*)(ga[t] + k0),
          (__attribute__((address_space(3))) void*)la[t], 16, 0, 0);
      __builtin_amdgcn_global_load_lds(
          (const __attribute__((address_space(1))) void*)(gb[t] + k0),
          (__attribute__((address_space(3))) void*)lb[t], 16, 0, 0);
    }
    __syncthreads();

#pragma unroll
    for (int ks = 0; ks < 2; ks++) {
      const int sq = ((quad + 4 * ks) ^ (fr & 7)) * 8;
      bf16x8 af[4], bfr[4];
#pragma unroll
      for (int i = 0; i < 4; i++) {
        af[i] = *(const bf16x8*)&As[(wm + i * 16 + fr) * 64 + sq];
        bfr[i] = *(const bf16x8*)&Bs[(wn + i * 16 + fr) * 64 + sq];
      }
#pragma unroll
      for (int i = 0; i < 4; i++)
#pragma unroll
        for (int j = 0; j < 4; j++)
          acc[i][j] = __builtin_amdgcn_mfma_f32_16x16x32_bf16(af[i], bfr[j],
                                                              acc[i][j], 0, 0, 0);
    }
  }

  // epilogue: C/D layout col=lane&15, row=quad*4+reg
  bf16_t* Pz = (mode == 4) ? ((bf16_t*)C + (size_t)z * M * N) : nullptr;
#pragma unroll
  for (int j = 0; j < 4; j++) {
    const int col = n0 + wn + j * 16 + fr;
    const float bj = bias ? bias[col] : 0.f;
#pragma unroll
    for (int i = 0; i < 4; i++) {
      const int rbase = m0 + wm + i * 16 + quad * 4;
#pragma unroll
      for (int r = 0; r < 4; r++) {
        const int row = rbase + r;
        float c = acc[i][j][r] + bj;
        if (mode == 1) {  // gelu(tanh) via fast sigmoid
          const float xg = c;
          const float t = 0.7978845608028654f * (xg + 0.044715f * xg * xg * xg);
          const float th = 2.0f / (1.0f + __expf(-2.0f * t)) - 1.0f;
          c = 0.5f * xg * (1.0f + th);
        }
        if (mode == 5) {  // fused residual: out += bias + gemm (fp32 RMW)
          float* O = (float*)C;
          O[(size_t)row * N + col] += c;
        } else if (mode == 4) {
          Pz[(size_t)row * N + col] = __float2bfloat16(c);
        } else {
          ((bf16_t*)C)[(size_t)row * N + col] = __float2bfloat16(c);
        }
      }
    }
  }
}

__global__ __launch_bounds__(256) void mgemm_kernel(const bf16_t* __restrict__ A,
                                                    const bf16_t* __restrict__ Bt,
                                                    const float* __restrict__ bias,
                                                    void* __restrict__ C,
                                                    int M, int N, int K, int Kc,
                                                    int Mt, int Nt, int PM,
                                                    int mode) {
  __shared__ bf16_t As[128 * 64];
  __shared__ bf16_t Bs[128 * 64];
  mgemm_body(A, Bt, bias, C, M, N, K, Kc, Mt, Nt, PM, mode, blockIdx.x, As, Bs);
}

// ---- merged QKV: blocks 0-511 = qk GEMM, 512-767 = vT GEMM (one launch) ----
__global__ __launch_bounds__(256) void qkv2_kernel(const bf16_t* __restrict__ h,
                                                   const bf16_t* __restrict__ wqkv_t,
                                                   bf16_t* __restrict__ qk,
                                                   bf16_t* __restrict__ vT) {
  __shared__ bf16_t As[128 * 64];
  __shared__ bf16_t Bs[128 * 64];
  if (blockIdx.x < 512) {
    // qk = h @ [wq|wk]: M=4096, N=2048 (Mt=8, Nt=8, PM=4)
    mgemm_body(h, wqkv_t, nullptr, qk, 4096, 2048, 1024, 1024, 8, 8, 4, 0,
               blockIdx.x, As, Bs);
  } else {
    // vT = wv_t (x) h: M=1024, N=4096 (Mt=4, Nt=8, PM=2)
    mgemm_body(wqkv_t + (size_t)2 * 1024 * 1024, h, nullptr, vT, 1024, 4096,
               1024, 1024, 4, 8, 2, 0, blockIdx.x - 512, As, Bs);
  }
}

// ---- 256x256-tile GEMM v5: 4-phase dbuf, 2 counted waits per K-tile --------
// Stage unit p of tile t+1 at phase p of tile t (order B0,B1,A0,A1).
// Waits: end-of-phase-0 vmcnt(2) covers A1(t) [leaves B0(t+1) flying];
// end-of-phase-3 vmcnt(2) covers B0,B1,A0(t+1) [leaves A1(t+1) flying].
// Never drains in steady state; each unit gets ~1 full K-tile of latency
// slack (vs 1-2 phases in the r5 variant). Phases 1,2: no vmcnt at all.
__global__ __launch_bounds__(512, 1) void mgemm256_kernel(
    const bf16_t* __restrict__ A, const bf16_t* __restrict__ Bt,
    const float* __restrict__ bias, void* __restrict__ C, int M, int N, int K,
    int Kc, int Mt, int Nt, int PM, int mode) {
  // [buf 0..1][ A[256][64] | B[256][64] ] = 2 * 64KB = 128 KB
  __shared__ bf16_t sm[65536];
  const int tid = threadIdx.x;
  const int lane = tid & 63, w = tid >> 6;

  const int flat = blockIdx.x;
  const int xcd = flat & 7;
  int t0 = flat >> 3;
  const int mb = xcd % PM, nb = xcd / PM;
  const int mt = mb * Mt + (t0 % Mt);
  t0 /= Mt;
  const int nt = nb * Nt + (t0 % Nt);
  const int z = t0 / Nt;
  const int m0 = mt * 256, n0 = nt * 256;
  const int kz0 = z * Kc;
  const int wr = (w >> 2) & 1, wc = w & 3;

  floatx4 zero = {0.f, 0.f, 0.f, 0.f};
  floatx4 acc[8][4];
#pragma unroll
  for (int i = 0; i < 8; i++)
#pragma unroll
    for (int j = 0; j < 4; j++) acc[i][j] = zero;

  const int r_t = tid >> 3;                                  // 0..63
  const int g8s = (((tid & 7) ^ (r_t & 7)) << 3);            // src col (elems)
  const int fr = lane & 15, quad = lane >> 4;

  // unit: 0 = B rows 0-127, 1 = B rows 128-255, 2 = A rows 0-127, 3 = A 128-255
  auto STAGE = [&](int nbuf, int unit, int kk) {
    const bf16_t* src0 =
        (unit < 2) ? Bt + (size_t)(n0 + (unit & 1) * 128 + r_t) * K + g8s + kk
                   : A + (size_t)(m0 + (unit & 1) * 128 + r_t) * K + g8s + kk;
    bf16_t* d0 = &sm[nbuf * 32768 + (unit < 2 ? 16384 : 0) + (unit & 1) * 8192 +
                     tid * 8];
#pragma unroll
    for (int l = 0; l < 2; ++l) {
      __builtin_amdgcn_global_load_lds(
          (const __attribute__((address_space(1))) void*)(src0 +
                                                          (size_t)l * 64 * K),
          (__attribute__((address_space(3))) void*)(d0 + l * 4096), 16, 0, 0);
    }
  };

  const int ntk = Kc >> 6;  // BK = 64

  // prologue: full tile 0 into buf 0 (units B0,B1,A0,A1)
  STAGE(0, 0, kz0); STAGE(0, 1, kz0); STAGE(0, 2, kz0); STAGE(0, 3, kz0);
  asm volatile("s_waitcnt vmcnt(2)" ::: "memory");  // B0,B1,A0 landed
  __builtin_amdgcn_s_barrier();

#define DO_PHASE(KS, MH, UNIT, WAIT)                                           \
  {                                                                            \
    const int sq = (((quad + 4 * (KS)) ^ (fr & 7)) << 3);                      \
    bf16x8 af[4];                                                              \
    _Pragma("unroll") for (int i = 0; i < 4; ++i) af[i] =                      \
        *(const bf16x8*)&sm[bo + ((MH)*128 + wr * 64 + i * 16 + fr) * 64 + sq];\
    if ((MH) == 0) {                                                           \
      _Pragma("unroll") for (int j = 0; j < 4; ++j) bfr[j] =                   \
          *(const bf16x8*)&sm[bo + 16384 + (wc * 64 + j * 16 + fr) * 64 + sq]; \
    }                                                                          \
    if (pre) STAGE(nbuf, (UNIT), kn);                                          \
    __builtin_amdgcn_s_barrier();                                              \
    asm volatile("s_waitcnt lgkmcnt(0)" ::: "memory");                         \
    __builtin_amdgcn_sched_barrier(0);                                         \
    __builtin_amdgcn_s_setprio(1);                                             \
    _Pragma("unroll") for (int i = 0; i < 4; ++i)                              \
        _Pragma("unroll") for (int j = 0; j < 4; ++j) acc[(MH)*4 + i][j] =     \
            __builtin_amdgcn_mfma_f32_16x16x32_bf16(af[i], bfr[j],             \
                                                    acc[(MH)*4 + i][j], 0, 0,  \
                                                    0);                        \
    __builtin_amdgcn_s_setprio(0);                                             \
    if (WAIT) {                                                                \
      if (pre) {                                                               \
        asm volatile("s_waitcnt vmcnt(2)" ::: "memory");                       \
      } else {                                                                 \
        asm volatile("s_waitcnt vmcnt(0)" ::: "memory");                       \
      }                                                                        \
    }                                                                          \
    __builtin_amdgcn_s_barrier();                                              \
  }

  for (int t = 0; t < ntk; ++t) {
    const int bo = (t & 1) * 32768;
    const int nbuf = (t + 1) & 1;
    const int kn = kz0 + (t + 1) * 64;
    const bool pre = (t + 1 < ntk);
    bf16x8 bfr[4];
    DO_PHASE(0, 0, 0, 1)  // ks0, mh0; stage B-h0(t+1); wait A1(t)
    DO_PHASE(0, 1, 1, 0)  // ks0, mh1; stage B-h1(t+1)
    DO_PHASE(1, 0, 2, 0)  // ks1, mh0; stage A-h0(t+1)
    DO_PHASE(1, 1, 3, 1)  // ks1, mh1; stage A-h1(t+1); wait B0,B1,A0(t+1)
  }
#undef DO_PHASE

  // ---- epilogue: per-wave 8KB LDS bounce -> 16B coalesced stores ----
  __syncthreads();
  bf16_t* sl = sm + w * 4096;  // 64 x 64 slice per wave
  bf16_t* Pz = (mode == 4) ? ((bf16_t*)C + (size_t)z * M * N) : (bf16_t*)C;
  float bj[4];
#pragma unroll
  for (int j = 0; j < 4; ++j)
    bj[j] = bias ? bias[n0 + wc * 64 + j * 16 + fr] : 0.f;
#pragma unroll
  for (int mh = 0; mh < 2; ++mh) {
    if (mh) {  // own-slice reuse: ensure pass-0 LDS reads fully drained
      asm volatile("s_waitcnt lgkmcnt(0)" ::: "memory");
      __builtin_amdgcn_sched_barrier(0);
    }
#pragma unroll
    for (int i = 0; i < 4; ++i)
#pragma unroll
      for (int j = 0; j < 4; ++j)
#pragma unroll
        for (int r = 0; r < 4; ++r) {
          const int rl = i * 16 + quad * 4 + r, cl = j * 16 + fr;
          float c = acc[mh * 4 + i][j][r] + bj[j];
          if (mode == 1) {  // gelu(tanh) via fast sigmoid
            const float xg = c;
            const float t2 =
                0.7978845608028654f * (xg + 0.044715f * xg * xg * xg);
            const float th = 2.0f / (1.0f + __expf(-2.0f * t2)) - 1.0f;
            c = 0.5f * xg * (1.0f + th);
          }
          const int cg = (cl >> 3) ^ (rl & 7);
          sl[rl * 64 + cg * 8 + (cl & 7)] = __float2bfloat16(c);
        }
#pragma unroll
    for (int it = 0; it < 8; ++it) {
      const int gi = it * 64 + lane;
      const int rl = gi >> 3, g = gi & 7;
      const bf16x8 vv = *(const bf16x8*)&sl[rl * 64 + ((g ^ (rl & 7)) * 8)];
      *(bf16x8*)&Pz[(size_t)(m0 + mh * 128 + wr * 64 + rl) * N + n0 + wc * 64 +
                    g * 8] = vv;
    }
  }
}

// --- fused: out = x + P + bias ; h = LN2(out). One block per row. -----------
__global__ __launch_bounds__(256) void reduce1_ln_kernel(
    const bf16_t* __restrict__ P, const float* __restrict__ x,
    const float* __restrict__ bias, const float* __restrict__ scale,
    const float* __restrict__ shift, float* __restrict__ out,
    bf16_t* __restrict__ h) {
  const int row = blockIdx.x;
  const size_t e = (size_t)row * D_ + threadIdx.x * 4;
  const float4 xv = *(const float4*)(x + e);
  const ushort4 p0 = *(const ushort4*)((const ushort*)P + e);
  const float4 bb = *(const float4*)(bias + threadIdx.x * 4);
  float4 v;
  v.x = xv.x + bf2f(p0.x) + bb.x;
  v.y = xv.y + bf2f(p0.y) + bb.y;
  v.z = xv.z + bf2f(p0.z) + bb.z;
  v.w = xv.w + bf2f(p0.w) + bb.w;
  *(float4*)(out + e) = v;

  float s = v.x + v.y + v.z + v.w;
  float ss = v.x * v.x + v.y * v.y + v.z * v.z + v.w * v.w;
#pragma unroll
  for (int off = 32; off > 0; off >>= 1) {
    s += __shfl_xor(s, off);
    ss += __shfl_xor(ss, off);
  }
  __shared__ float ls[4], lss[4], stats[2];
  const int wave = threadIdx.x >> 6, lane = threadIdx.x & 63;
  if (lane == 0) { ls[wave] = s; lss[wave] = ss; }
  __syncthreads();
  if (threadIdx.x == 0) {
    float t = ls[0] + ls[1] + ls[2] + ls[3];
    float tt = lss[0] + lss[1] + lss[2] + lss[3];
    float mean = t * (1.0f / D_);
    stats[0] = mean;
    stats[1] = rsqrtf(tt * (1.0f / D_) - mean * mean + 1e-5f);
  }
  __syncthreads();
  const float mean = stats[0], rstd = stats[1];
  const float4 sc = *(const float4*)(scale + threadIdx.x * 4);
  const float4 sh = *(const float4*)(shift + threadIdx.x * 4);
  bf16_t ob[4];
  ob[0] = __float2bfloat16(sc.x * (v.x - mean) * rstd + sh.x);
  ob[1] = __float2bfloat16(sc.y * (v.y - mean) * rstd + sh.y);
  ob[2] = __float2bfloat16(sc.z * (v.z - mean) * rstd + sh.z);
  ob[3] = __float2bfloat16(sc.w * (v.w - mean) * rstd + sh.w);
  *(ushort4*)(h + e) = *(ushort4*)ob;
}

// ---------------- MFMA flash attention v2 (fixed-max softmax) ---------------
// QK: [4096][2048] bf16, Q at col h*64, K at col 1024+h*64.
// VT: [1024][4096] bf16, row = h*64+d, col = b*1024+s  (V pre-transposed).
__global__ __launch_bounds__(256) void fattn_kernel(const bf16_t* __restrict__ QK,
                                                    const bf16_t* __restrict__ VT,
                                                    const int* __restrict__ mask,
                                                    bf16_t* __restrict__ O) {
  const int qt = gridDim.x - 1 - blockIdx.x;  // heavy tiles first
  const int h = blockIdx.y, b = blockIdx.z;
  const int tid = threadIdx.x;
  const int lane = tid & 63, w = tid >> 6;
  const int tx = lane & 15, quad = lane >> 4;
  const int q0 = qt * 64;

  __shared__ bf16_t Ks[64 * 64];  // K-tile [j][d], swizzled granules
  __shared__ bf16_t Vs[64 * 64];  // V^T-tile [d][j], swizzled granules
  __shared__ ushort Ps[64 * 64];  // P [q][j], swizzled granules

  // staging: chunk c (8 rows x 128B), c = w + 4t
  const int ro8 = lane >> 3;
  const int g8 = ((lane & 7) ^ ro8) * 8;  // swizzled source granule
  const bf16_t* gk[2];
  const bf16_t* gv[2];
  bf16_t* lk[2];
  bf16_t* lv[2];
#pragma unroll
  for (int t = 0; t < 2; t++) {
    const int c = w + 4 * t;
    gk[t] = QK + (size_t)((size_t)b * S_ + c * 8 + ro8) * 2048 + 1024 + h * HD_ + g8;
    gv[t] = VT + (size_t)(h * HD_ + c * 8 + ro8) * 4096 + (size_t)b * S_ + g8;
    lk[t] = &Ks[c * 512];
    lv[t] = &Vs[c * 512];
  }

  // Q fragments: rows q0 + w*16 + tx, packed d = ks*32 + quad*8
  bf16x8 qf[2];
#pragma unroll
  for (int ks = 0; ks < 2; ks++)
    qf[ks] = *(const bf16x8*)(QK + (size_t)((size_t)b * S_ + q0 + w * 16 + tx) * 2048 +
                              h * HD_ + ks * 32 + quad * 8);

  const short oneb = 0x3F80;  // bf16 1.0
  bf16x8 vones = {oneb, oneb, oneb, oneb, oneb, oneb, oneb, oneb};

  floatx4 ctx[4], lacc;
#pragma unroll
  for (int nt = 0; nt < 4; nt++) {
    ctx[nt].x = 0.f; ctx[nt].y = 0.f; ctx[nt].z = 0.f; ctx[nt].w = 0.f;
  }
  lacc.x = 0.f; lacc.y = 0.f; lacc.z = 0.f; lacc.w = 0.f;

  for (int kt = 0; kt <= qt; kt++) {
    const int k0 = kt * 64;
    __syncthreads();
#pragma unroll
    for (int t = 0; t < 2; t++) {
      __builtin_amdgcn_global_load_lds(
          (const __attribute__((address_space(1))) void*)(gk[t] + (size_t)k0 * 2048),
          (__attribute__((address_space(3))) void*)lk[t], 16, 0, 0);
      __builtin_amdgcn_global_load_lds(
          (const __attribute__((address_space(1))) void*)(gv[t] + k0),
          (__attribute__((address_space(3))) void*)lv[t], 16, 0, 0);
    }
    __syncthreads();

    // ---- S = Q K^T ----
    floatx4 accS[4];
#pragma unroll
    for (int nt = 0; nt < 4; nt++) {
      accS[nt].x = 0.f; accS[nt].y = 0.f; accS[nt].z = 0.f; accS[nt].w = 0.f;
    }
#pragma unroll
    for (int ks = 0; ks < 2; ks++) {
      const int sq = ((quad + 4 * ks) ^ (tx & 7)) * 8;
      bf16x8 kf[4];
#pragma unroll
      for (int nt = 0; nt < 4; nt++)
        kf[nt] = *(const bf16x8*)&Ks[(nt * 16 + tx) * 64 + sq];
#pragma unroll
      for (int nt = 0; nt < 4; nt++)
        accS[nt] = __builtin_amdgcn_mfma_f32_16x16x32_bf16(qf[ks], kf[nt],
                                                           accS[nt], 0, 0, 0);
    }

    // ---- P = exp(S/8), mask, store swizzled ----
#pragma unroll
    for (int nt = 0; nt < 4; nt++) {
      const int jc = k0 + nt * 16 + tx;
      const bool ok = mask[b * S_ + jc] != 0;
      const int col = nt * 16 + tx;
#pragma unroll
      for (int r = 0; r < 4; r++) {
        const int qq = quad * 4 + r;
        const int qrow = q0 + w * 16 + qq;
        float p = exp2f(accS[nt][r] * 0.1803368801111244f);  // 0.125*log2(e)
        if (jc > qrow || !ok) p = 0.f;
        const int pc = ((((col >> 3) ^ (qq & 7)) << 3)) | (col & 7);
        Ps[(w * 16 + qq) * 64 + pc] =
            ((__hip_bfloat16_raw)__float2bfloat16(p)).x;
      }
    }

    // ---- ctx += P V ---- (same-wave Ps write->read, no barrier needed)
#pragma unroll
    for (int ks = 0; ks < 2; ks++) {
      const int sq = ((quad + 4 * ks) ^ (tx & 7)) * 8;
      const bf16x8 pf = *(const bf16x8*)&Ps[(w * 16 + tx) * 64 + sq];
      bf16x8 vf[4];
#pragma unroll
      for (int nt = 0; nt < 4; nt++)
        vf[nt] = *(const bf16x8*)&Vs[(nt * 16 + tx) * 64 + sq];
#pragma unroll
      for (int nt = 0; nt < 4; nt++)
        ctx[nt] = __builtin_amdgcn_mfma_f32_16x16x32_bf16(pf, vf[nt],
                                                          ctx[nt], 0, 0, 0);
      lacc = __builtin_amdgcn_mfma_f32_16x16x32_bf16(pf, vones, lacc, 0, 0, 0);
    }
  }

  const size_t obase = (size_t)b * S_ * D_ + (size_t)h * HD_;
  float rinv[4];
#pragma unroll
  for (int r = 0; r < 4; r++) rinv[r] = 1.0f / lacc[r];
#pragma unroll
  for (int nt = 0; nt < 4; nt++)
#pragma unroll
    for (int r = 0; r < 4; r++) {
      const int q = q0 + w * 16 + quad * 4 + r;
      O[obase + (size_t)q * D_ + nt * 16 + tx] =
          __float2bfloat16(ctx[nt][r] * rinv[r]);
    }
}

extern "C" void kernel_launch(void* const* d_in, const int* in_sizes, int n_in,
                              void* d_out, int out_size, void* d_ws, size_t ws_size,
                              hipStream_t stream) {
  const float* x = (const float*)d_in[0];
  const int* mask = (const int*)d_in[1];
  const float* wq = (const float*)d_in[2];
  const float* wk = (const float*)d_in[3];
  const float* wv = (const float*)d_in[4];
  const float* wo = (const float*)d_in[5];
  const float* bo = (const float*)d_in[6];
  const float* ln2s = (const float*)d_in[9];
  const float* ln2b = (const float*)d_in[10];
  const float* w1 = (const float*)d_in[11];
  const float* b1 = (const float*)d_in[12];
  const float* w2 = (const float*)d_in[13];
  const float* b2 = (const float*)d_in[14];
  float* out = (float*)d_out;

  const int M = B_ * S_;  // 4096
  char* ws = (char*)d_ws;
  const size_t MB = (size_t)1 << 20;
  bf16_t* qk = (bf16_t*)(ws);                  // [4096][2048] = 16 MB
  bf16_t* vT = (bf16_t*)(ws + 16 * MB);        // [1024][4096] = 8 MB
  bf16_t* ffn1 = (bf16_t*)(ws);                // step 6: qk/vT dead, 32 MB
  bf16_t* ctx = (bf16_t*)(ws + 32 * MB);       // 8 MB
  bf16_t* h = (bf16_t*)(ws + 40 * MB);         // 8 MB
  bf16_t* wqkv_t = (bf16_t*)(ws + 48 * MB);    // [3072,1024] = 6 MB
  bf16_t* wo_t = (bf16_t*)(ws + 54 * MB);      // [1024,1024] = 2 MB
  bf16_t* w1_t = (bf16_t*)(ws + 56 * MB);      // [4096,1024] = 8 MB
  bf16_t* w2_t = (bf16_t*)(ws + 64 * MB);      // [1024,4096] = 8 MB
  bf16_t* Pa = (bf16_t*)(ws + 24 * MB);        // step 4: 8 MB (qk dead region)

  // 1. prep: h = LN1(x) + all weight transposes (one launch)
  prep_kernel<<<dim3(16384), 256, 0, stream>>>(x, (const float*)d_in[7],
                                               (const float*)d_in[8], h, wq, wk,
                                               wv, wo, w1, w2, wqkv_t, wo_t,
                                               w1_t, w2_t);

  // 2. merged: qk = h @ [wq|wk] (512 blocks) + vT = wv_t (x) h (256 blocks)
  qkv2_kernel<<<dim3(768), 256, 0, stream>>>(h, wqkv_t, qk, vT);

  // 3. ctx = softmax(causal(q k^T)/8) v -> bf16 (MFMA flash v2)
  fattn_kernel<<<dim3(S_ / 64, H_, B_), 256, 0, stream>>>(qk, vT, mask, ctx);

  // 4. attn-out, no split-K: Pa = ctx @ wo  (256 blocks; PM=8, Mt=4, Nt=8)
  mgemm_kernel<<<dim3(256), 256, 0, stream>>>(
      ctx, wo_t, nullptr, Pa, M, D_, D_, D_, /*Mt=*/4, /*Nt=*/8, /*PM=*/8, 0);

  // 5. out = x + Pa + bo ; h = LN2(out)   (fused)
  reduce1_ln_kernel<<<dim3(M), 256, 0, stream>>>(Pa, x, bo, ln2s, ln2b, out, h);

  // 6. ffn1 = gelu(h @ w1 + b1)  (256^2 tiles: 16x16 = 256 blocks, 1/CU)
  mgemm256_kernel<<<dim3(256), 512, 0, stream>>>(
      h, w1_t, b1, ffn1, M, 4 * D_, D_, D_, /*Mt=*/4, /*Nt=*/8, /*PM=*/4, 1);

  // 7. ffn2 fused: out += b2 + ffn1 @ w2  (K=4096 plain, 256 blocks, fp32 RMW)
  mgemm_kernel<<<dim3(256), 256, 0, stream>>>(
      ffn1, w2_t, b2, out, M, D_, 4 * D_, 4 * D_, /*Mt=*/8, /*Nt=*/4, /*PM=*/4,
      5);
}

// Round 7
// 343.561 us; speedup vs baseline: 1.1203x; 1.1203x over previous
//
#include <hip/hip_runtime.h>
#include <hip/hip_bf16.h>
#include <math.h>

#define B_ 4
#define S_ 1024
#define D_ 1024
#define H_ 16
#define HD_ 64

typedef __hip_bfloat16 bf16_t;
typedef __attribute__((ext_vector_type(8))) short bf16x8;
typedef __attribute__((ext_vector_type(4))) float floatx4;

__device__ __forceinline__ float bf2f(ushort u) {
  return __uint_as_float((unsigned)u << 16);
}

// ---- prep: one launch = LN1 (4096 row-blocks) + all 6 weight transposes ----
__global__ __launch_bounds__(256) void prep_kernel(
    const float* __restrict__ x, const float* __restrict__ ln1s,
    const float* __restrict__ ln1b, bf16_t* __restrict__ h,
    const float* __restrict__ wq, const float* __restrict__ wk,
    const float* __restrict__ wv, const float* __restrict__ wo,
    const float* __restrict__ w1, const float* __restrict__ w2,
    bf16_t* __restrict__ wqkv_t, bf16_t* __restrict__ wo_t,
    bf16_t* __restrict__ w1_t, bf16_t* __restrict__ w2_t) {
  const int id = blockIdx.x;
  if (id < 4096) {  // ---- LayerNorm row ----
    const int row = id;
    float4 v = ((const float4*)(x + (size_t)row * D_))[threadIdx.x];
    float s = v.x + v.y + v.z + v.w;
    float ss = v.x * v.x + v.y * v.y + v.z * v.z + v.w * v.w;
#pragma unroll
    for (int off = 32; off > 0; off >>= 1) {
      s += __shfl_xor(s, off);
      ss += __shfl_xor(ss, off);
    }
    __shared__ float ls[4], lss[4], stats[2];
    const int wave = threadIdx.x >> 6, lane = threadIdx.x & 63;
    if (lane == 0) { ls[wave] = s; lss[wave] = ss; }
    __syncthreads();
    if (threadIdx.x == 0) {
      float t = ls[0] + ls[1] + ls[2] + ls[3];
      float tt = lss[0] + lss[1] + lss[2] + lss[3];
      float mean = t * (1.0f / D_);
      stats[0] = mean;
      stats[1] = rsqrtf(tt * (1.0f / D_) - mean * mean + 1e-5f);
    }
    __syncthreads();
    const float mean = stats[0], rstd = stats[1];
    float4 sc = ((const float4*)ln1s)[threadIdx.x];
    float4 sh = ((const float4*)ln1b)[threadIdx.x];
    bf16_t ob[4];
    ob[0] = __float2bfloat16(sc.x * (v.x - mean) * rstd + sh.x);
    ob[1] = __float2bfloat16(sc.y * (v.y - mean) * rstd + sh.y);
    ob[2] = __float2bfloat16(sc.z * (v.z - mean) * rstd + sh.z);
    ob[3] = __float2bfloat16(sc.w * (v.w - mean) * rstd + sh.w);
    *(ushort4*)(h + (size_t)row * D_ + threadIdx.x * 4) = *(ushort4*)ob;
    return;
  }
  const float* W;
  bf16_t* Wt;
  int K, N, n0, k0;
  if (id < 8192) {
    const int t = id - 4096, which = t >> 10, tile = t & 1023;
    n0 = (tile & 31) * 32;
    k0 = (tile >> 5) * 32;
    K = 1024; N = 1024;
    W = which == 0 ? wq : which == 1 ? wk : which == 2 ? wv : wo;
    Wt = which < 3 ? wqkv_t + (size_t)which * 1024 * 1024 : wo_t;
  } else if (id < 12288) {
    const int tile = id - 8192;
    n0 = (tile & 127) * 32;
    k0 = (tile >> 7) * 32;
    K = 1024; N = 4096;
    W = w1; Wt = w1_t;
  } else {
    const int tile = id - 12288;
    n0 = (tile & 31) * 32;
    k0 = (tile >> 5) * 32;
    K = 4096; N = 1024;
    W = w2; Wt = w2_t;
  }
  __shared__ float t[32][33];
  const int lx = threadIdx.x & 31, ly = threadIdx.x >> 5;  // 32 x 8
#pragma unroll
  for (int r = ly; r < 32; r += 8) t[r][lx] = W[(size_t)(k0 + r) * N + n0 + lx];
  __syncthreads();
#pragma unroll
  for (int r = ly; r < 32; r += 8)
    Wt[(size_t)(n0 + r) * K + k0 + lx] = __float2bfloat16(t[lx][r]);
}

// ------------- bf16 MFMA GEMM body: 128x128 tile, BK=64, XCD-clustered ------
// mode 0: C bf16 | 1: bias+gelu -> C bf16 | 4: bf16 partial + z*M*N (split-K)
// NOTE: keep grids >= 512 blocks (>=2 blocks/CU) — at 1 block/CU the per-tile
// barrier drain has no co-resident block to hide under (round-6: 93us ffn2).
__device__ __forceinline__ void mgemm_body(
    const bf16_t* __restrict__ A, const bf16_t* __restrict__ Bt,
    const float* __restrict__ bias, void* __restrict__ C, int M, int N, int K,
    int Kc, int Mt, int Nt, int PM, int mode, int flat, bf16_t* As,
    bf16_t* Bs) {
  const int tid = threadIdx.x;
  const int lane = tid & 63, w = tid >> 6;

  // --- XCD-cluster decode ---
  const int xcd = flat & 7;
  int t0 = flat >> 3;
  const int mb = xcd % PM, nb = xcd / PM;
  const int mt = mb * Mt + (t0 % Mt);
  t0 /= Mt;
  const int nt = nb * Nt + (t0 % Nt);
  const int z = t0 / Nt;
  const int m0 = mt * 128, n0 = nt * 128;
  const int kz0 = z * Kc;
  const int wm = (w >> 1) * 64, wn = (w & 1) * 64;

  floatx4 zero = {0.f, 0.f, 0.f, 0.f};
  floatx4 acc[4][4];
#pragma unroll
  for (int i = 0; i < 4; i++)
#pragma unroll
    for (int j = 0; j < 4; j++) acc[i][j] = zero;

  // staging: chunk c (1KB = 8 rows x 128B) handled by wave c&3, c = w+4t.
  const int ro8 = lane >> 3;                 // row within chunk
  const int g8 = ((lane & 7) ^ ro8) * 8;     // swizzled source col (elements)
  const bf16_t* ga[4];
  const bf16_t* gb[4];
  bf16_t* la[4];
  bf16_t* lb[4];
#pragma unroll
  for (int t = 0; t < 4; t++) {
    const int c = w + 4 * t;
    ga[t] = A + (size_t)(m0 + c * 8 + ro8) * K + g8;
    gb[t] = Bt + (size_t)(n0 + c * 8 + ro8) * K + g8;
    la[t] = &As[c * 512];
    lb[t] = &Bs[c * 512];
  }

  const int fr = lane & 15, quad = lane >> 4;

  for (int k0 = kz0; k0 < kz0 + Kc; k0 += 64) {
    __syncthreads();
#pragma unroll
    for (int t = 0; t < 4; t++) {
      __builtin_amdgcn_global_load_lds(
          (const __attribute__((address_space(1))) void*)(ga[t] + k0),
          (__attribute__((address_space(3))) void*)la[t], 16, 0, 0);
      __builtin_amdgcn_global_load_lds(
          (const __attribute__((address_space(1))) void*)(gb[t] + k0),
          (__attribute__((address_space(3))) void*)lb[t], 16, 0, 0);
    }
    __syncthreads();

#pragma unroll
    for (int ks = 0; ks < 2; ks++) {
      const int sq = ((quad + 4 * ks) ^ (fr & 7)) * 8;
      bf16x8 af[4], bfr[4];
#pragma unroll
      for (int i = 0; i < 4; i++) {
        af[i] = *(const bf16x8*)&As[(wm + i * 16 + fr) * 64 + sq];
        bfr[i] = *(const bf16x8*)&Bs[(wn + i * 16 + fr) * 64 + sq];
      }
#pragma unroll
      for (int i = 0; i < 4; i++)
#pragma unroll
        for (int j = 0; j < 4; j++)
          acc[i][j] = __builtin_amdgcn_mfma_f32_16x16x32_bf16(af[i], bfr[j],
                                                              acc[i][j], 0, 0, 0);
    }
  }

  // epilogue: C/D layout col=lane&15, row=quad*4+reg
  bf16_t* Pz = (mode == 4) ? ((bf16_t*)C + (size_t)z * M * N) : nullptr;
#pragma unroll
  for (int j = 0; j < 4; j++) {
    const int col = n0 + wn + j * 16 + fr;
    const float bj = bias ? bias[col] : 0.f;
#pragma unroll
    for (int i = 0; i < 4; i++) {
      const int rbase = m0 + wm + i * 16 + quad * 4;
#pragma unroll
      for (int r = 0; r < 4; r++) {
        const int row = rbase + r;
        float c = acc[i][j][r] + bj;
        if (mode == 1) {  // gelu(tanh) via fast sigmoid
          const float xg = c;
          const float t = 0.7978845608028654f * (xg + 0.044715f * xg * xg * xg);
          const float th = 2.0f / (1.0f + __expf(-2.0f * t)) - 1.0f;
          c = 0.5f * xg * (1.0f + th);
        }
        if (mode == 4) {
          Pz[(size_t)row * N + col] = __float2bfloat16(c);
        } else {
          ((bf16_t*)C)[(size_t)row * N + col] = __float2bfloat16(c);
        }
      }
    }
  }
}

__global__ __launch_bounds__(256) void mgemm_kernel(const bf16_t* __restrict__ A,
                                                    const bf16_t* __restrict__ Bt,
                                                    const float* __restrict__ bias,
                                                    void* __restrict__ C,
                                                    int M, int N, int K, int Kc,
                                                    int Mt, int Nt, int PM,
                                                    int mode) {
  __shared__ bf16_t As[128 * 64];
  __shared__ bf16_t Bs[128 * 64];
  mgemm_body(A, Bt, bias, C, M, N, K, Kc, Mt, Nt, PM, mode, blockIdx.x, As, Bs);
}

// ---- merged QKV: blocks 0-511 = qk GEMM, 512-767 = vT GEMM (one launch) ----
__global__ __launch_bounds__(256) void qkv2_kernel(const bf16_t* __restrict__ h,
                                                   const bf16_t* __restrict__ wqkv_t,
                                                   bf16_t* __restrict__ qk,
                                                   bf16_t* __restrict__ vT) {
  __shared__ bf16_t As[128 * 64];
  __shared__ bf16_t Bs[128 * 64];
  if (blockIdx.x < 512) {
    // qk = h @ [wq|wk]: M=4096, N=2048 (Mt=8, Nt=8, PM=4)
    mgemm_body(h, wqkv_t, nullptr, qk, 4096, 2048, 1024, 1024, 8, 8, 4, 0,
               blockIdx.x, As, Bs);
  } else {
    // vT = wv_t (x) h: M=1024, N=4096 (Mt=4, Nt=8, PM=2)
    mgemm_body(wqkv_t + (size_t)2 * 1024 * 1024, h, nullptr, vT, 1024, 4096,
               1024, 1024, 4, 8, 2, 0, blockIdx.x - 512, As, Bs);
  }
}

// ---- 256x256-tile GEMM: 4-phase dbuf, 2 counted waits per K-tile -----------
// (best measured config for the big FFN GEMMs: ~55us @ M=4096,N=4096,K=1024)
__global__ __launch_bounds__(512, 1) void mgemm256_kernel(
    const bf16_t* __restrict__ A, const bf16_t* __restrict__ Bt,
    const float* __restrict__ bias, void* __restrict__ C, int M, int N, int K,
    int Kc, int Mt, int Nt, int PM, int mode) {
  // [buf 0..1][ A[256][64] | B[256][64] ] = 2 * 64KB = 128 KB
  __shared__ bf16_t sm[65536];
  const int tid = threadIdx.x;
  const int lane = tid & 63, w = tid >> 6;

  const int flat = blockIdx.x;
  const int xcd = flat & 7;
  int t0 = flat >> 3;
  const int mb = xcd % PM, nb = xcd / PM;
  const int mt = mb * Mt + (t0 % Mt);
  t0 /= Mt;
  const int nt = nb * Nt + (t0 % Nt);
  const int z = t0 / Nt;
  const int m0 = mt * 256, n0 = nt * 256;
  const int kz0 = z * Kc;
  const int wr = (w >> 2) & 1, wc = w & 3;

  floatx4 zero = {0.f, 0.f, 0.f, 0.f};
  floatx4 acc[8][4];
#pragma unroll
  for (int i = 0; i < 8; i++)
#pragma unroll
    for (int j = 0; j < 4; j++) acc[i][j] = zero;

  const int r_t = tid >> 3;                                  // 0..63
  const int g8s = (((tid & 7) ^ (r_t & 7)) << 3);            // src col (elems)
  const int fr = lane & 15, quad = lane >> 4;

  // unit: 0 = B rows 0-127, 1 = B rows 128-255, 2 = A rows 0-127, 3 = A 128-255
  auto STAGE = [&](int nbuf, int unit, int kk) {
    const bf16_t* src0 =
        (unit < 2) ? Bt + (size_t)(n0 + (unit & 1) * 128 + r_t) * K + g8s + kk
                   : A + (size_t)(m0 + (unit & 1) * 128 + r_t) * K + g8s + kk;
    bf16_t* d0 = &sm[nbuf * 32768 + (unit < 2 ? 16384 : 0) + (unit & 1) * 8192 +
                     tid * 8];
#pragma unroll
    for (int l = 0; l < 2; ++l) {
      __builtin_amdgcn_global_load_lds(
          (const __attribute__((address_space(1))) void*)(src0 +
                                                          (size_t)l * 64 * K),
          (__attribute__((address_space(3))) void*)(d0 + l * 4096), 16, 0, 0);
    }
  };

  const int ntk = Kc >> 6;  // BK = 64

  // prologue: full tile 0 into buf 0 (units B0,B1,A0,A1)
  STAGE(0, 0, kz0); STAGE(0, 1, kz0); STAGE(0, 2, kz0); STAGE(0, 3, kz0);
  asm volatile("s_waitcnt vmcnt(2)" ::: "memory");  // B0,B1,A0 landed
  __builtin_amdgcn_s_barrier();

#define DO_PHASE(KS, MH, UNIT, WAIT)                                           \
  {                                                                            \
    const int sq = (((quad + 4 * (KS)) ^ (fr & 7)) << 3);                      \
    bf16x8 af[4];                                                              \
    _Pragma("unroll") for (int i = 0; i < 4; ++i) af[i] =                      \
        *(const bf16x8*)&sm[bo + ((MH)*128 + wr * 64 + i * 16 + fr) * 64 + sq];\
    if ((MH) == 0) {                                                           \
      _Pragma("unroll") for (int j = 0; j < 4; ++j) bfr[j] =                   \
          *(const bf16x8*)&sm[bo + 16384 + (wc * 64 + j * 16 + fr) * 64 + sq]; \
    }                                                                          \
    if (pre) STAGE(nbuf, (UNIT), kn);                                          \
    __builtin_amdgcn_s_barrier();                                              \
    asm volatile("s_waitcnt lgkmcnt(0)" ::: "memory");                         \
    __builtin_amdgcn_sched_barrier(0);                                         \
    __builtin_amdgcn_s_setprio(1);                                             \
    _Pragma("unroll") for (int i = 0; i < 4; ++i)                              \
        _Pragma("unroll") for (int j = 0; j < 4; ++j) acc[(MH)*4 + i][j] =     \
            __builtin_amdgcn_mfma_f32_16x16x32_bf16(af[i], bfr[j],             \
                                                    acc[(MH)*4 + i][j], 0, 0,  \
                                                    0);                        \
    __builtin_amdgcn_s_setprio(0);                                             \
    if (WAIT) {                                                                \
      if (pre) {                                                               \
        asm volatile("s_waitcnt vmcnt(2)" ::: "memory");                       \
      } else {                                                                 \
        asm volatile("s_waitcnt vmcnt(0)" ::: "memory");                       \
      }                                                                        \
    }                                                                          \
    __builtin_amdgcn_s_barrier();                                              \
  }

  for (int t = 0; t < ntk; ++t) {
    const int bo = (t & 1) * 32768;
    const int nbuf = (t + 1) & 1;
    const int kn = kz0 + (t + 1) * 64;
    const bool pre = (t + 1 < ntk);
    bf16x8 bfr[4];
    DO_PHASE(0, 0, 0, 1)  // ks0, mh0; stage B-h0(t+1); wait A1(t)
    DO_PHASE(0, 1, 1, 0)  // ks0, mh1; stage B-h1(t+1)
    DO_PHASE(1, 0, 2, 0)  // ks1, mh0; stage A-h0(t+1)
    DO_PHASE(1, 1, 3, 1)  // ks1, mh1; stage A-h1(t+1); wait B0,B1,A0(t+1)
  }
#undef DO_PHASE

  // ---- epilogue: per-wave 8KB LDS bounce -> 16B coalesced stores ----
  __syncthreads();
  bf16_t* sl = sm + w * 4096;  // 64 x 64 slice per wave
  bf16_t* Pz = (mode == 4) ? ((bf16_t*)C + (size_t)z * M * N) : (bf16_t*)C;
  float bj[4];
#pragma unroll
  for (int j = 0; j < 4; ++j)
    bj[j] = bias ? bias[n0 + wc * 64 + j * 16 + fr] : 0.f;
#pragma unroll
  for (int mh = 0; mh < 2; ++mh) {
    if (mh) {  // own-slice reuse: ensure pass-0 LDS reads fully drained
      asm volatile("s_waitcnt lgkmcnt(0)" ::: "memory");
      __builtin_amdgcn_sched_barrier(0);
    }
#pragma unroll
    for (int i = 0; i < 4; ++i)
#pragma unroll
      for (int j = 0; j < 4; ++j)
#pragma unroll
        for (int r = 0; r < 4; ++r) {
          const int rl = i * 16 + quad * 4 + r, cl = j * 16 + fr;
          float c = acc[mh * 4 + i][j][r] + bj[j];
          if (mode == 1) {  // gelu(tanh) via fast sigmoid
            const float xg = c;
            const float t2 =
                0.7978845608028654f * (xg + 0.044715f * xg * xg * xg);
            const float th = 2.0f / (1.0f + __expf(-2.0f * t2)) - 1.0f;
            c = 0.5f * xg * (1.0f + th);
          }
          const int cg = (cl >> 3) ^ (rl & 7);
          sl[rl * 64 + cg * 8 + (cl & 7)] = __float2bfloat16(c);
        }
#pragma unroll
    for (int it = 0; it < 8; ++it) {
      const int gi = it * 64 + lane;
      const int rl = gi >> 3, g = gi & 7;
      const bf16x8 vv = *(const bf16x8*)&sl[rl * 64 + ((g ^ (rl & 7)) * 8)];
      *(bf16x8*)&Pz[(size_t)(m0 + mh * 128 + wr * 64 + rl) * N + n0 + wc * 64 +
                    g * 8] = vv;
    }
  }
}

// --- fused: out = x + P0 + P1 + bias ; h = LN2(out). One block per row. -----
__global__ __launch_bounds__(256) void reduce2_ln_kernel(
    const bf16_t* __restrict__ P, size_t slice, const float* __restrict__ x,
    const float* __restrict__ bias, const float* __restrict__ scale,
    const float* __restrict__ shift, float* __restrict__ out,
    bf16_t* __restrict__ h) {
  const int row = blockIdx.x;
  const size_t e = (size_t)row * D_ + threadIdx.x * 4;
  const float4 xv = *(const float4*)(x + e);
  const ushort4 p0 = *(const ushort4*)((const ushort*)P + e);
  const ushort4 p1 = *(const ushort4*)((const ushort*)P + slice + e);
  const float4 bb = *(const float4*)(bias + threadIdx.x * 4);
  float4 v;
  v.x = xv.x + bf2f(p0.x) + bf2f(p1.x) + bb.x;
  v.y = xv.y + bf2f(p0.y) + bf2f(p1.y) + bb.y;
  v.z = xv.z + bf2f(p0.z) + bf2f(p1.z) + bb.z;
  v.w = xv.w + bf2f(p0.w) + bf2f(p1.w) + bb.w;
  *(float4*)(out + e) = v;

  float s = v.x + v.y + v.z + v.w;
  float ss = v.x * v.x + v.y * v.y + v.z * v.z + v.w * v.w;
#pragma unroll
  for (int off = 32; off > 0; off >>= 1) {
    s += __shfl_xor(s, off);
    ss += __shfl_xor(ss, off);
  }
  __shared__ float ls[4], lss[4], stats[2];
  const int wave = threadIdx.x >> 6, lane = threadIdx.x & 63;
  if (lane == 0) { ls[wave] = s; lss[wave] = ss; }
  __syncthreads();
  if (threadIdx.x == 0) {
    float t = ls[0] + ls[1] + ls[2] + ls[3];
    float tt = lss[0] + lss[1] + lss[2] + lss[3];
    float mean = t * (1.0f / D_);
    stats[0] = mean;
    stats[1] = rsqrtf(tt * (1.0f / D_) - mean * mean + 1e-5f);
  }
  __syncthreads();
  const float mean = stats[0], rstd = stats[1];
  const float4 sc = *(const float4*)(scale + threadIdx.x * 4);
  const float4 sh = *(const float4*)(shift + threadIdx.x * 4);
  bf16_t ob[4];
  ob[0] = __float2bfloat16(sc.x * (v.x - mean) * rstd + sh.x);
  ob[1] = __float2bfloat16(sc.y * (v.y - mean) * rstd + sh.y);
  ob[2] = __float2bfloat16(sc.z * (v.z - mean) * rstd + sh.z);
  ob[3] = __float2bfloat16(sc.w * (v.w - mean) * rstd + sh.w);
  *(ushort4*)(h + e) = *(ushort4*)ob;
}

// --- split-K x4 reduce: out = out + P0+P1+P2+P3 + bias (P bf16) -------------
__global__ __launch_bounds__(256) void reduce4_kernel(const bf16_t* __restrict__ P,
                                                      size_t slice,
                                                      const float* __restrict__ bias,
                                                      float* __restrict__ out,
                                                      int N) {
  const size_t e = ((size_t)blockIdx.x * 256 + threadIdx.x) * 4;
  const ushort* Pu = (const ushort*)P;
  const ushort4 p0 = *(const ushort4*)(Pu + e);
  const ushort4 p1 = *(const ushort4*)(Pu + slice + e);
  const ushort4 p2 = *(const ushort4*)(Pu + 2 * slice + e);
  const ushort4 p3 = *(const ushort4*)(Pu + 3 * slice + e);
  const float4 r = *(const float4*)(out + e);
  const float4 bb = *(const float4*)(bias + (int)(e % N));
  float4 o;
  o.x = r.x + bb.x + bf2f(p0.x) + bf2f(p1.x) + bf2f(p2.x) + bf2f(p3.x);
  o.y = r.y + bb.y + bf2f(p0.y) + bf2f(p1.y) + bf2f(p2.y) + bf2f(p3.y);
  o.z = r.z + bb.z + bf2f(p0.z) + bf2f(p1.z) + bf2f(p2.z) + bf2f(p3.z);
  o.w = r.w + bb.w + bf2f(p0.w) + bf2f(p1.w) + bf2f(p2.w) + bf2f(p3.w);
  *(float4*)(out + e) = o;
}

// ---------------- MFMA flash attention v2 (fixed-max softmax) ---------------
// QK: [4096][2048] bf16, Q at col h*64, K at col 1024+h*64.
// VT: [1024][4096] bf16, row = h*64+d, col = b*1024+s  (V pre-transposed).
__global__ __launch_bounds__(256) void fattn_kernel(const bf16_t* __restrict__ QK,
                                                    const bf16_t* __restrict__ VT,
                                                    const int* __restrict__ mask,
                                                    bf16_t* __restrict__ O) {
  const int qt = gridDim.x - 1 - blockIdx.x;  // heavy tiles first
  const int h = blockIdx.y, b = blockIdx.z;
  const int tid = threadIdx.x;
  const int lane = tid & 63, w = tid >> 6;
  const int tx = lane & 15, quad = lane >> 4;
  const int q0 = qt * 64;

  __shared__ bf16_t Ks[64 * 64];  // K-tile [j][d], swizzled granules
  __shared__ bf16_t Vs[64 * 64];  // V^T-tile [d][j], swizzled granules
  __shared__ ushort Ps[64 * 64];  // P [q][j], swizzled granules

  // staging: chunk c (8 rows x 128B), c = w + 4t
  const int ro8 = lane >> 3;
  const int g8 = ((lane & 7) ^ ro8) * 8;  // swizzled source granule
  const bf16_t* gk[2];
  const bf16_t* gv[2];
  bf16_t* lk[2];
  bf16_t* lv[2];
#pragma unroll
  for (int t = 0; t < 2; t++) {
    const int c = w + 4 * t;
    gk[t] = QK + (size_t)((size_t)b * S_ + c * 8 + ro8) * 2048 + 1024 + h * HD_ + g8;
    gv[t] = VT + (size_t)(h * HD_ + c * 8 + ro8) * 4096 + (size_t)b * S_ + g8;
    lk[t] = &Ks[c * 512];
    lv[t] = &Vs[c * 512];
  }

  // Q fragments: rows q0 + w*16 + tx, packed d = ks*32 + quad*8
  bf16x8 qf[2];
#pragma unroll
  for (int ks = 0; ks < 2; ks++)
    qf[ks] = *(const bf16x8*)(QK + (size_t)((size_t)b * S_ + q0 + w * 16 + tx) * 2048 +
                              h * HD_ + ks * 32 + quad * 8);

  const short oneb = 0x3F80;  // bf16 1.0
  bf16x8 vones = {oneb, oneb, oneb, oneb, oneb, oneb, oneb, oneb};

  floatx4 ctx[4], lacc;
#pragma unroll
  for (int nt = 0; nt < 4; nt++) {
    ctx[nt].x = 0.f; ctx[nt].y = 0.f; ctx[nt].z = 0.f; ctx[nt].w = 0.f;
  }
  lacc.x = 0.f; lacc.y = 0.f; lacc.z = 0.f; lacc.w = 0.f;

  for (int kt = 0; kt <= qt; kt++) {
    const int k0 = kt * 64;
    __syncthreads();
#pragma unroll
    for (int t = 0; t < 2; t++) {
      __builtin_amdgcn_global_load_lds(
          (const __attribute__((address_space(1))) void*)(gk[t] + (size_t)k0 * 2048),
          (__attribute__((address_space(3))) void*)lk[t], 16, 0, 0);
      __builtin_amdgcn_global_load_lds(
          (const __attribute__((address_space(1))) void*)(gv[t] + k0),
          (__attribute__((address_space(3))) void*)lv[t], 16, 0, 0);
    }
    __syncthreads();

    // ---- S = Q K^T ----
    floatx4 accS[4];
#pragma unroll
    for (int nt = 0; nt < 4; nt++) {
      accS[nt].x = 0.f; accS[nt].y = 0.f; accS[nt].z = 0.f; accS[nt].w = 0.f;
    }
#pragma unroll
    for (int ks = 0; ks < 2; ks++) {
      const int sq = ((quad + 4 * ks) ^ (tx & 7)) * 8;
      bf16x8 kf[4];
#pragma unroll
      for (int nt = 0; nt < 4; nt++)
        kf[nt] = *(const bf16x8*)&Ks[(nt * 16 + tx) * 64 + sq];
#pragma unroll
      for (int nt = 0; nt < 4; nt++)
        accS[nt] = __builtin_amdgcn_mfma_f32_16x16x32_bf16(qf[ks], kf[nt],
                                                           accS[nt], 0, 0, 0);
    }

    // ---- P = exp(S/8), mask, store swizzled ----
#pragma unroll
    for (int nt = 0; nt < 4; nt++) {
      const int jc = k0 + nt * 16 + tx;
      const bool ok = mask[b * S_ + jc] != 0;
      const int col = nt * 16 + tx;
#pragma unroll
      for (int r = 0; r < 4; r++) {
        const int qq = quad * 4 + r;
        const int qrow = q0 + w * 16 + qq;
        float p = exp2f(accS[nt][r] * 0.1803368801111244f);  // 0.125*log2(e)
        if (jc > qrow || !ok) p = 0.f;
        const int pc = ((((col >> 3) ^ (qq & 7)) << 3)) | (col & 7);
        Ps[(w * 16 + qq) * 64 + pc] =
            ((__hip_bfloat16_raw)__float2bfloat16(p)).x;
      }
    }

    // ---- ctx += P V ---- (same-wave Ps write->read, no barrier needed)
#pragma unroll
    for (int ks = 0; ks < 2; ks++) {
      const int sq = ((quad + 4 * ks) ^ (tx & 7)) * 8;
      const bf16x8 pf = *(const bf16x8*)&Ps[(w * 16 + tx) * 64 + sq];
      bf16x8 vf[4];
#pragma unroll
      for (int nt = 0; nt < 4; nt++)
        vf[nt] = *(const bf16x8*)&Vs[(nt * 16 + tx) * 64 + sq];
#pragma unroll
      for (int nt = 0; nt < 4; nt++)
        ctx[nt] = __builtin_amdgcn_mfma_f32_16x16x32_bf16(pf, vf[nt],
                                                          ctx[nt], 0, 0, 0);
      lacc = __builtin_amdgcn_mfma_f32_16x16x32_bf16(pf, vones, lacc, 0, 0, 0);
    }
  }

  const size_t obase = (size_t)b * S_ * D_ + (size_t)h * HD_;
  float rinv[4];
#pragma unroll
  for (int r = 0; r < 4; r++) rinv[r] = 1.0f / lacc[r];
#pragma unroll
  for (int nt = 0; nt < 4; nt++)
#pragma unroll
    for (int r = 0; r < 4; r++) {
      const int q = q0 + w * 16 + quad * 4 + r;
      O[obase + (size_t)q * D_ + nt * 16 + tx] =
          __float2bfloat16(ctx[nt][r] * rinv[r]);
    }
}

extern "C" void kernel_launch(void* const* d_in, const int* in_sizes, int n_in,
                              void* d_out, int out_size, void* d_ws, size_t ws_size,
                              hipStream_t stream) {
  const float* x = (const float*)d_in[0];
  const int* mask = (const int*)d_in[1];
  const float* wq = (const float*)d_in[2];
  const float* wk = (const float*)d_in[3];
  const float* wv = (const float*)d_in[4];
  const float* wo = (const float*)d_in[5];
  const float* bo = (const float*)d_in[6];
  const float* ln2s = (const float*)d_in[9];
  const float* ln2b = (const float*)d_in[10];
  const float* w1 = (const float*)d_in[11];
  const float* b1 = (const float*)d_in[12];
  const float* w2 = (const float*)d_in[13];
  const float* b2 = (const float*)d_in[14];
  float* out = (float*)d_out;

  const int M = B_ * S_;  // 4096
  char* ws = (char*)d_ws;
  const size_t MB = (size_t)1 << 20;
  bf16_t* qk = (bf16_t*)(ws);                  // [4096][2048] = 16 MB
  bf16_t* vT = (bf16_t*)(ws + 16 * MB);        // [1024][4096] = 8 MB
  bf16_t* ffn1 = (bf16_t*)(ws);                // step 6: qk/vT/Pa dead, 32 MB
  bf16_t* ctx = (bf16_t*)(ws + 32 * MB);       // 8 MB
  bf16_t* h = (bf16_t*)(ws + 40 * MB);         // 8 MB
  bf16_t* wqkv_t = (bf16_t*)(ws + 48 * MB);    // [3072,1024] = 6 MB
  bf16_t* wo_t = (bf16_t*)(ws + 54 * MB);      // [1024,1024] = 2 MB
  bf16_t* w1_t = (bf16_t*)(ws + 56 * MB);      // [4096,1024] = 8 MB
  bf16_t* w2_t = (bf16_t*)(ws + 64 * MB);      // [1024,4096] = 8 MB
  bf16_t* Pa = (bf16_t*)(ws);                  // step 4: qk/vT dead, 2x8MB
  bf16_t* Pf = (bf16_t*)(ws + 32 * MB);        // step 7: ctx/h/w*_t dead, 4x8MB
  const size_t slice = (size_t)M * D_;

  // 1. prep: h = LN1(x) + all weight transposes (one launch)
  prep_kernel<<<dim3(16384), 256, 0, stream>>>(x, (const float*)d_in[7],
                                               (const float*)d_in[8], h, wq, wk,
                                               wv, wo, w1, w2, wqkv_t, wo_t,
                                               w1_t, w2_t);

  // 2. merged: qk = h @ [wq|wk] (512 blocks) + vT = wv_t (x) h (256 blocks)
  qkv2_kernel<<<dim3(768), 256, 0, stream>>>(h, wqkv_t, qk, vT);

  // 3. ctx = softmax(causal(q k^T)/8) v -> bf16 (MFMA flash v2)
  fattn_kernel<<<dim3(S_ / 64, H_, B_), 256, 0, stream>>>(qk, vT, mask, ctx);

  // 4. attn-out split-K x2 (512 blocks, >=2/CU; PM=8,PN=1)
  mgemm_kernel<<<dim3(8 * 32 * 2), 256, 0, stream>>>(
      ctx, wo_t, nullptr, Pa, M, D_, D_, D_ / 2, /*Mt=*/4, /*Nt=*/8, /*PM=*/8, 4);

  // 5. out = x + Pa0 + Pa1 + bo ; h = LN2(out)   (fused)
  reduce2_ln_kernel<<<dim3(M), 256, 0, stream>>>(Pa, slice, x, bo, ln2s, ln2b,
                                                 out, h);

  // 6. ffn1 = gelu(h @ w1 + b1)  (256^2 tiles: 16x16 = 256 blocks)
  mgemm256_kernel<<<dim3(256), 512, 0, stream>>>(
      h, w1_t, b1, ffn1, M, 4 * D_, D_, D_, /*Mt=*/4, /*Nt=*/8, /*PM=*/4, 1);

  // 7. ffn2 split-K x4 (256^2 tiles: 16x4 x 4z = 256 blocks; PM=8,PN=1)
  mgemm256_kernel<<<dim3(256), 512, 0, stream>>>(
      ffn1, w2_t, nullptr, Pf, M, D_, 4 * D_, D_, /*Mt=*/2, /*Nt=*/4, /*PM=*/8, 4);

  // 8. out = out + sum(Pf) + b2
  reduce4_kernel<<<dim3((size_t)M * D_ / 1024), 256, 0, stream>>>(
      Pf, slice, b2, out, D_);
}

// Round 8
// 340.808 us; speedup vs baseline: 1.1294x; 1.0081x over previous
//
#include <hip/hip_runtime.h>
#include <hip/hip_bf16.h>
#include <math.h>

#define B_ 4
#define S_ 1024
#define D_ 1024
#define H_ 16
#define HD_ 64

typedef __hip_bfloat16 bf16_t;
typedef __attribute__((ext_vector_type(8))) short bf16x8;
typedef __attribute__((ext_vector_type(4))) float floatx4;

__device__ __forceinline__ float bf2f(ushort u) {
  return __uint_as_float((unsigned)u << 16);
}

// ---- prep: one launch = LN1 (4096 row-blocks) + all 6 weight transposes ----
__global__ __launch_bounds__(256) void prep_kernel(
    const float* __restrict__ x, const float* __restrict__ ln1s,
    const float* __restrict__ ln1b, bf16_t* __restrict__ h,
    const float* __restrict__ wq, const float* __restrict__ wk,
    const float* __restrict__ wv, const float* __restrict__ wo,
    const float* __restrict__ w1, const float* __restrict__ w2,
    bf16_t* __restrict__ wqkv_t, bf16_t* __restrict__ wo_t,
    bf16_t* __restrict__ w1_t, bf16_t* __restrict__ w2_t) {
  const int id = blockIdx.x;
  if (id < 4096) {  // ---- LayerNorm row ----
    const int row = id;
    float4 v = ((const float4*)(x + (size_t)row * D_))[threadIdx.x];
    float s = v.x + v.y + v.z + v.w;
    float ss = v.x * v.x + v.y * v.y + v.z * v.z + v.w * v.w;
#pragma unroll
    for (int off = 32; off > 0; off >>= 1) {
      s += __shfl_xor(s, off);
      ss += __shfl_xor(ss, off);
    }
    __shared__ float ls[4], lss[4], stats[2];
    const int wave = threadIdx.x >> 6, lane = threadIdx.x & 63;
    if (lane == 0) { ls[wave] = s; lss[wave] = ss; }
    __syncthreads();
    if (threadIdx.x == 0) {
      float t = ls[0] + ls[1] + ls[2] + ls[3];
      float tt = lss[0] + lss[1] + lss[2] + lss[3];
      float mean = t * (1.0f / D_);
      stats[0] = mean;
      stats[1] = rsqrtf(tt * (1.0f / D_) - mean * mean + 1e-5f);
    }
    __syncthreads();
    const float mean = stats[0], rstd = stats[1];
    float4 sc = ((const float4*)ln1s)[threadIdx.x];
    float4 sh = ((const float4*)ln1b)[threadIdx.x];
    bf16_t ob[4];
    ob[0] = __float2bfloat16(sc.x * (v.x - mean) * rstd + sh.x);
    ob[1] = __float2bfloat16(sc.y * (v.y - mean) * rstd + sh.y);
    ob[2] = __float2bfloat16(sc.z * (v.z - mean) * rstd + sh.z);
    ob[3] = __float2bfloat16(sc.w * (v.w - mean) * rstd + sh.w);
    *(ushort4*)(h + (size_t)row * D_ + threadIdx.x * 4) = *(ushort4*)ob;
    return;
  }
  const float* W;
  bf16_t* Wt;
  int K, N, n0, k0;
  if (id < 8192) {
    const int t = id - 4096, which = t >> 10, tile = t & 1023;
    n0 = (tile & 31) * 32;
    k0 = (tile >> 5) * 32;
    K = 1024; N = 1024;
    W = which == 0 ? wq : which == 1 ? wk : which == 2 ? wv : wo;
    Wt = which < 3 ? wqkv_t + (size_t)which * 1024 * 1024 : wo_t;
  } else if (id < 12288) {
    const int tile = id - 8192;
    n0 = (tile & 127) * 32;
    k0 = (tile >> 7) * 32;
    K = 1024; N = 4096;
    W = w1; Wt = w1_t;
  } else {
    const int tile = id - 12288;
    n0 = (tile & 31) * 32;
    k0 = (tile >> 5) * 32;
    K = 4096; N = 1024;
    W = w2; Wt = w2_t;
  }
  __shared__ float t[32][33];
  const int lx = threadIdx.x & 31, ly = threadIdx.x >> 5;  // 32 x 8
#pragma unroll
  for (int r = ly; r < 32; r += 8) t[r][lx] = W[(size_t)(k0 + r) * N + n0 + lx];
  __syncthreads();
#pragma unroll
  for (int r = ly; r < 32; r += 8)
    Wt[(size_t)(n0 + r) * K + k0 + lx] = __float2bfloat16(t[lx][r]);
}

// ------------- bf16 MFMA GEMM body: 128x128 tile, BK=64, XCD-clustered ------
// mode 0: C bf16 | 1: bias+gelu -> C bf16 | 4: bf16 partial + z*M*N (split-K)
// NOTE: keep grids >= 512 blocks (>=2 blocks/CU) — at 1 block/CU this 4-wave
// kernel has no co-resident block to hide the barrier drain (round-6: 93us).
__device__ __forceinline__ void mgemm_body(
    const bf16_t* __restrict__ A, const bf16_t* __restrict__ Bt,
    const float* __restrict__ bias, void* __restrict__ C, int M, int N, int K,
    int Kc, int Mt, int Nt, int PM, int mode, int flat, bf16_t* As,
    bf16_t* Bs) {
  const int tid = threadIdx.x;
  const int lane = tid & 63, w = tid >> 6;

  // --- XCD-cluster decode ---
  const int xcd = flat & 7;
  int t0 = flat >> 3;
  const int mb = xcd % PM, nb = xcd / PM;
  const int mt = mb * Mt + (t0 % Mt);
  t0 /= Mt;
  const int nt = nb * Nt + (t0 % Nt);
  const int z = t0 / Nt;
  const int m0 = mt * 128, n0 = nt * 128;
  const int kz0 = z * Kc;
  const int wm = (w >> 1) * 64, wn = (w & 1) * 64;

  floatx4 zero = {0.f, 0.f, 0.f, 0.f};
  floatx4 acc[4][4];
#pragma unroll
  for (int i = 0; i < 4; i++)
#pragma unroll
    for (int j = 0; j < 4; j++) acc[i][j] = zero;

  // staging: chunk c (1KB = 8 rows x 128B) handled by wave c&3, c = w+4t.
  const int ro8 = lane >> 3;                 // row within chunk
  const int g8 = ((lane & 7) ^ ro8) * 8;     // swizzled source col (elements)
  const bf16_t* ga[4];
  const bf16_t* gb[4];
  bf16_t* la[4];
  bf16_t* lb[4];
#pragma unroll
  for (int t = 0; t < 4; t++) {
    const int c = w + 4 * t;
    ga[t] = A + (size_t)(m0 + c * 8 + ro8) * K + g8;
    gb[t] = Bt + (size_t)(n0 + c * 8 + ro8) * K + g8;
    la[t] = &As[c * 512];
    lb[t] = &Bs[c * 512];
  }

  const int fr = lane & 15, quad = lane >> 4;

  for (int k0 = kz0; k0 < kz0 + Kc; k0 += 64) {
    __syncthreads();
#pragma unroll
    for (int t = 0; t < 4; t++) {
      __builtin_amdgcn_global_load_lds(
          (const __attribute__((address_space(1))) void*)(ga[t] + k0),
          (__attribute__((address_space(3))) void*)la[t], 16, 0, 0);
      __builtin_amdgcn_global_load_lds(
          (const __attribute__((address_space(1))) void*)(gb[t] + k0),
          (__attribute__((address_space(3))) void*)lb[t], 16, 0, 0);
    }
    __syncthreads();

#pragma unroll
    for (int ks = 0; ks < 2; ks++) {
      const int sq = ((quad + 4 * ks) ^ (fr & 7)) * 8;
      bf16x8 af[4], bfr[4];
#pragma unroll
      for (int i = 0; i < 4; i++) {
        af[i] = *(const bf16x8*)&As[(wm + i * 16 + fr) * 64 + sq];
        bfr[i] = *(const bf16x8*)&Bs[(wn + i * 16 + fr) * 64 + sq];
      }
#pragma unroll
      for (int i = 0; i < 4; i++)
#pragma unroll
        for (int j = 0; j < 4; j++)
          acc[i][j] = __builtin_amdgcn_mfma_f32_16x16x32_bf16(af[i], bfr[j],
                                                              acc[i][j], 0, 0, 0);
    }
  }

  // epilogue: C/D layout col=lane&15, row=quad*4+reg
  bf16_t* Pz = (mode == 4) ? ((bf16_t*)C + (size_t)z * M * N) : nullptr;
#pragma unroll
  for (int j = 0; j < 4; j++) {
    const int col = n0 + wn + j * 16 + fr;
    const float bj = bias ? bias[col] : 0.f;
#pragma unroll
    for (int i = 0; i < 4; i++) {
      const int rbase = m0 + wm + i * 16 + quad * 4;
#pragma unroll
      for (int r = 0; r < 4; r++) {
        const int row = rbase + r;
        float c = acc[i][j][r] + bj;
        if (mode == 1) {  // gelu(tanh) via fast sigmoid
          const float xg = c;
          const float t = 0.7978845608028654f * (xg + 0.044715f * xg * xg * xg);
          const float th = 2.0f / (1.0f + __expf(-2.0f * t)) - 1.0f;
          c = 0.5f * xg * (1.0f + th);
        }
        if (mode == 4) {
          Pz[(size_t)row * N + col] = __float2bfloat16(c);
        } else {
          ((bf16_t*)C)[(size_t)row * N + col] = __float2bfloat16(c);
        }
      }
    }
  }
}

__global__ __launch_bounds__(256) void mgemm_kernel(const bf16_t* __restrict__ A,
                                                    const bf16_t* __restrict__ Bt,
                                                    const float* __restrict__ bias,
                                                    void* __restrict__ C,
                                                    int M, int N, int K, int Kc,
                                                    int Mt, int Nt, int PM,
                                                    int mode) {
  __shared__ bf16_t As[128 * 64];
  __shared__ bf16_t Bs[128 * 64];
  mgemm_body(A, Bt, bias, C, M, N, K, Kc, Mt, Nt, PM, mode, blockIdx.x, As, Bs);
}

// ---- merged QKV: blocks 0-511 = qk GEMM, 512-767 = vT GEMM (one launch) ----
__global__ __launch_bounds__(256) void qkv2_kernel(const bf16_t* __restrict__ h,
                                                   const bf16_t* __restrict__ wqkv_t,
                                                   bf16_t* __restrict__ qk,
                                                   bf16_t* __restrict__ vT) {
  __shared__ bf16_t As[128 * 64];
  __shared__ bf16_t Bs[128 * 64];
  if (blockIdx.x < 512) {
    // qk = h @ [wq|wk]: M=4096, N=2048 (Mt=8, Nt=8, PM=4)
    mgemm_body(h, wqkv_t, nullptr, qk, 4096, 2048, 1024, 1024, 8, 8, 4, 0,
               blockIdx.x, As, Bs);
  } else {
    // vT = wv_t (x) h: M=1024, N=4096 (Mt=4, Nt=8, PM=2)
    mgemm_body(wqkv_t + (size_t)2 * 1024 * 1024, h, nullptr, vT, 1024, 4096,
               1024, 1024, 4, 8, 2, 0, blockIdx.x - 512, As, Bs);
  }
}

// ---- 256x256-tile GEMM: 4-phase dbuf; ALL of tile t+1 staged at phase 0 ----
// Dependency analysis (r7 post-mortem): every wave's reads need its A-half
// (unit 2+wr) and B-half (unit wc>>1), and consumption of ALL units begins at
// phase 0 of the next tile. Staging one unit/phase gives the last unit only
// ~1 phase of landing slack (< L2 latency). Staging all 4 units at phase 0
// gives a uniform >=3-phase (~1000 cyc) slack, covering HBM-miss latency.
// The boundary vmcnt(0) then drains loads issued 3 phases ago (nominal).
__global__ __launch_bounds__(512, 1) void mgemm256_kernel(
    const bf16_t* __restrict__ A, const bf16_t* __restrict__ Bt,
    const float* __restrict__ bias, void* __restrict__ C, int M, int N, int K,
    int Kc, int Mt, int Nt, int PM, int mode) {
  // [buf 0..1][ A[256][64] | B[256][64] ] = 2 * 64KB = 128 KB
  __shared__ bf16_t sm[65536];
  const int tid = threadIdx.x;
  const int lane = tid & 63, w = tid >> 6;

  const int flat = blockIdx.x;
  const int xcd = flat & 7;
  int t0 = flat >> 3;
  const int mb = xcd % PM, nb = xcd / PM;
  const int mt = mb * Mt + (t0 % Mt);
  t0 /= Mt;
  const int nt = nb * Nt + (t0 % Nt);
  const int z = t0 / Nt;
  const int m0 = mt * 256, n0 = nt * 256;
  const int kz0 = z * Kc;
  const int wr = (w >> 2) & 1, wc = w & 3;

  floatx4 zero = {0.f, 0.f, 0.f, 0.f};
  floatx4 acc[8][4];
#pragma unroll
  for (int i = 0; i < 8; i++)
#pragma unroll
    for (int j = 0; j < 4; j++) acc[i][j] = zero;

  const int r_t = tid >> 3;                                  // 0..63
  const int g8s = (((tid & 7) ^ (r_t & 7)) << 3);            // src col (elems)
  const int fr = lane & 15, quad = lane >> 4;

  // unit: 0 = B rows 0-127, 1 = B rows 128-255, 2 = A rows 0-127, 3 = A 128-255
  auto STAGE = [&](int nbuf, int unit, int kk) {
    const bf16_t* src0 =
        (unit < 2) ? Bt + (size_t)(n0 + (unit & 1) * 128 + r_t) * K + g8s + kk
                   : A + (size_t)(m0 + (unit & 1) * 128 + r_t) * K + g8s + kk;
    bf16_t* d0 = &sm[nbuf * 32768 + (unit < 2 ? 16384 : 0) + (unit & 1) * 8192 +
                     tid * 8];
#pragma unroll
    for (int l = 0; l < 2; ++l) {
      __builtin_amdgcn_global_load_lds(
          (const __attribute__((address_space(1))) void*)(src0 +
                                                          (size_t)l * 64 * K),
          (__attribute__((address_space(3))) void*)(d0 + l * 4096), 16, 0, 0);
    }
  };

  const int ntk = Kc >> 6;  // BK = 64

  // prologue: full tile 0 into buf 0
  STAGE(0, 0, kz0); STAGE(0, 1, kz0); STAGE(0, 2, kz0); STAGE(0, 3, kz0);
  asm volatile("s_waitcnt vmcnt(0)" ::: "memory");
  __builtin_amdgcn_s_barrier();

#define DO_PHASE(KS, MH, STG, WAIT)                                            \
  {                                                                            \
    const int sq = (((quad + 4 * (KS)) ^ (fr & 7)) << 3);                      \
    bf16x8 af[4];                                                              \
    _Pragma("unroll") for (int i = 0; i < 4; ++i) af[i] =                      \
        *(const bf16x8*)&sm[bo + ((MH)*128 + wr * 64 + i * 16 + fr) * 64 + sq];\
    if ((MH) == 0) {                                                           \
      _Pragma("unroll") for (int j = 0; j < 4; ++j) bfr[j] =                   \
          *(const bf16x8*)&sm[bo + 16384 + (wc * 64 + j * 16 + fr) * 64 + sq]; \
    }                                                                          \
    if ((STG) && pre) {                                                        \
      STAGE(nbuf, 0, kn); STAGE(nbuf, 1, kn);                                  \
      STAGE(nbuf, 2, kn); STAGE(nbuf, 3, kn);                                  \
    }                                                                          \
    __builtin_amdgcn_s_barrier();                                              \
    asm volatile("s_waitcnt lgkmcnt(0)" ::: "memory");                         \
    __builtin_amdgcn_sched_barrier(0);                                         \
    __builtin_amdgcn_s_setprio(1);                                             \
    _Pragma("unroll") for (int i = 0; i < 4; ++i)                              \
        _Pragma("unroll") for (int j = 0; j < 4; ++j) acc[(MH)*4 + i][j] =     \
            __builtin_amdgcn_mfma_f32_16x16x32_bf16(af[i], bfr[j],             \
                                                    acc[(MH)*4 + i][j], 0, 0,  \
                                                    0);                        \
    __builtin_amdgcn_s_setprio(0);                                             \
    if (WAIT) asm volatile("s_waitcnt vmcnt(0)" ::: "memory");                 \
    __builtin_amdgcn_s_barrier();                                              \
  }

  for (int t = 0; t < ntk; ++t) {
    const int bo = (t & 1) * 32768;
    const int nbuf = (t + 1) & 1;
    const int kn = kz0 + (t + 1) * 64;
    const bool pre = (t + 1 < ntk);
    bf16x8 bfr[4];
    DO_PHASE(0, 0, 1, 0)  // ks0, mh0; stage ALL of tile t+1
    DO_PHASE(0, 1, 0, 0)  // ks0, mh1
    DO_PHASE(1, 0, 0, 0)  // ks1, mh0
    DO_PHASE(1, 1, 0, 1)  // ks1, mh1; drain (loads are 3 phases old)
  }
#undef DO_PHASE

  // ---- epilogue: per-wave 8KB LDS bounce -> 16B coalesced stores ----
  __syncthreads();
  bf16_t* sl = sm + w * 4096;  // 64 x 64 slice per wave
  bf16_t* Pz = (mode == 4) ? ((bf16_t*)C + (size_t)z * M * N) : (bf16_t*)C;
  float bj[4];
#pragma unroll
  for (int j = 0; j < 4; ++j)
    bj[j] = bias ? bias[n0 + wc * 64 + j * 16 + fr] : 0.f;
#pragma unroll
  for (int mh = 0; mh < 2; ++mh) {
    if (mh) {  // own-slice reuse: ensure pass-0 LDS reads fully drained
      asm volatile("s_waitcnt lgkmcnt(0)" ::: "memory");
      __builtin_amdgcn_sched_barrier(0);
    }
#pragma unroll
    for (int i = 0; i < 4; ++i)
#pragma unroll
      for (int j = 0; j < 4; ++j)
#pragma unroll
        for (int r = 0; r < 4; ++r) {
          const int rl = i * 16 + quad * 4 + r, cl = j * 16 + fr;
          float c = acc[mh * 4 + i][j][r] + bj[j];
          if (mode == 1) {  // gelu(tanh) via fast sigmoid
            const float xg = c;
            const float t2 =
                0.7978845608028654f * (xg + 0.044715f * xg * xg * xg);
            const float th = 2.0f / (1.0f + __expf(-2.0f * t2)) - 1.0f;
            c = 0.5f * xg * (1.0f + th);
          }
          const int cg = (cl >> 3) ^ (rl & 7);
          sl[rl * 64 + cg * 8 + (cl & 7)] = __float2bfloat16(c);
        }
#pragma unroll
    for (int it = 0; it < 8; ++it) {
      const int gi = it * 64 + lane;
      const int rl = gi >> 3, g = gi & 7;
      const bf16x8 vv = *(const bf16x8*)&sl[rl * 64 + ((g ^ (rl & 7)) * 8)];
      *(bf16x8*)&Pz[(size_t)(m0 + mh * 128 + wr * 64 + rl) * N + n0 + wc * 64 +
                    g * 8] = vv;
    }
  }
}

// --- fused: out = x + P0 + P1 + bias ; h = LN2(out). One block per row. -----
__global__ __launch_bounds__(256) void reduce2_ln_kernel(
    const bf16_t* __restrict__ P, size_t slice, const float* __restrict__ x,
    const float* __restrict__ bias, const float* __restrict__ scale,
    const float* __restrict__ shift, float* __restrict__ out,
    bf16_t* __restrict__ h) {
  const int row = blockIdx.x;
  const size_t e = (size_t)row * D_ + threadIdx.x * 4;
  const float4 xv = *(const float4*)(x + e);
  const ushort4 p0 = *(const ushort4*)((const ushort*)P + e);
  const ushort4 p1 = *(const ushort4*)((const ushort*)P + slice + e);
  const float4 bb = *(const float4*)(bias + threadIdx.x * 4);
  float4 v;
  v.x = xv.x + bf2f(p0.x) + bf2f(p1.x) + bb.x;
  v.y = xv.y + bf2f(p0.y) + bf2f(p1.y) + bb.y;
  v.z = xv.z + bf2f(p0.z) + bf2f(p1.z) + bb.z;
  v.w = xv.w + bf2f(p0.w) + bf2f(p1.w) + bb.w;
  *(float4*)(out + e) = v;

  float s = v.x + v.y + v.z + v.w;
  float ss = v.x * v.x + v.y * v.y + v.z * v.z + v.w * v.w;
#pragma unroll
  for (int off = 32; off > 0; off >>= 1) {
    s += __shfl_xor(s, off);
    ss += __shfl_xor(ss, off);
  }
  __shared__ float ls[4], lss[4], stats[2];
  const int wave = threadIdx.x >> 6, lane = threadIdx.x & 63;
  if (lane == 0) { ls[wave] = s; lss[wave] = ss; }
  __syncthreads();
  if (threadIdx.x == 0) {
    float t = ls[0] + ls[1] + ls[2] + ls[3];
    float tt = lss[0] + lss[1] + lss[2] + lss[3];
    float mean = t * (1.0f / D_);
    stats[0] = mean;
    stats[1] = rsqrtf(tt * (1.0f / D_) - mean * mean + 1e-5f);
  }
  __syncthreads();
  const float mean = stats[0], rstd = stats[1];
  const float4 sc = *(const float4*)(scale + threadIdx.x * 4);
  const float4 sh = *(const float4*)(shift + threadIdx.x * 4);
  bf16_t ob[4];
  ob[0] = __float2bfloat16(sc.x * (v.x - mean) * rstd + sh.x);
  ob[1] = __float2bfloat16(sc.y * (v.y - mean) * rstd + sh.y);
  ob[2] = __float2bfloat16(sc.z * (v.z - mean) * rstd + sh.z);
  ob[3] = __float2bfloat16(sc.w * (v.w - mean) * rstd + sh.w);
  *(ushort4*)(h + e) = *(ushort4*)ob;
}

// --- split-K x4 reduce: out = out + P0+P1+P2+P3 + bias (P bf16) -------------
__global__ __launch_bounds__(256) void reduce4_kernel(const bf16_t* __restrict__ P,
                                                      size_t slice,
                                                      const float* __restrict__ bias,
                                                      float* __restrict__ out,
                                                      int N) {
  const size_t e = ((size_t)blockIdx.x * 256 + threadIdx.x) * 4;
  const ushort* Pu = (const ushort*)P;
  const ushort4 p0 = *(const ushort4*)(Pu + e);
  const ushort4 p1 = *(const ushort4*)(Pu + slice + e);
  const ushort4 p2 = *(const ushort4*)(Pu + 2 * slice + e);
  const ushort4 p3 = *(const ushort4*)(Pu + 3 * slice + e);
  const float4 r = *(const float4*)(out + e);
  const float4 bb = *(const float4*)(bias + (int)(e % N));
  float4 o;
  o.x = r.x + bb.x + bf2f(p0.x) + bf2f(p1.x) + bf2f(p2.x) + bf2f(p3.x);
  o.y = r.y + bb.y + bf2f(p0.y) + bf2f(p1.y) + bf2f(p2.y) + bf2f(p3.y);
  o.z = r.z + bb.z + bf2f(p0.z) + bf2f(p1.z) + bf2f(p2.z) + bf2f(p3.z);
  o.w = r.w + bb.w + bf2f(p0.w) + bf2f(p1.w) + bf2f(p2.w) + bf2f(p3.w);
  *(float4*)(out + e) = o;
}

// ---------------- MFMA flash attention v2 (fixed-max softmax) ---------------
// QK: [4096][2048] bf16, Q at col h*64, K at col 1024+h*64.
// VT: [1024][4096] bf16, row = h*64+d, col = b*1024+s  (V pre-transposed).
__global__ __launch_bounds__(256) void fattn_kernel(const bf16_t* __restrict__ QK,
                                                    const bf16_t* __restrict__ VT,
                                                    const int* __restrict__ mask,
                                                    bf16_t* __restrict__ O) {
  const int qt = gridDim.x - 1 - blockIdx.x;  // heavy tiles first
  const int h = blockIdx.y, b = blockIdx.z;
  const int tid = threadIdx.x;
  const int lane = tid & 63, w = tid >> 6;
  const int tx = lane & 15, quad = lane >> 4;
  const int q0 = qt * 64;

  __shared__ bf16_t Ks[64 * 64];  // K-tile [j][d], swizzled granules
  __shared__ bf16_t Vs[64 * 64];  // V^T-tile [d][j], swizzled granules
  __shared__ ushort Ps[64 * 64];  // P [q][j], swizzled granules

  // staging: chunk c (8 rows x 128B), c = w + 4t
  const int ro8 = lane >> 3;
  const int g8 = ((lane & 7) ^ ro8) * 8;  // swizzled source granule
  const bf16_t* gk[2];
  const bf16_t* gv[2];
  bf16_t* lk[2];
  bf16_t* lv[2];
#pragma unroll
  for (int t = 0; t < 2; t++) {
    const int c = w + 4 * t;
    gk[t] = QK + (size_t)((size_t)b * S_ + c * 8 + ro8) * 2048 + 1024 + h * HD_ + g8;
    gv[t] = VT + (size_t)(h * HD_ + c * 8 + ro8) * 4096 + (size_t)b * S_ + g8;
    lk[t] = &Ks[c * 512];
    lv[t] = &Vs[c * 512];
  }

  // Q fragments: rows q0 + w*16 + tx, packed d = ks*32 + quad*8
  bf16x8 qf[2];
#pragma unroll
  for (int ks = 0; ks < 2; ks++)
    qf[ks] = *(const bf16x8*)(QK + (size_t)((size_t)b * S_ + q0 + w * 16 + tx) * 2048 +
                              h * HD_ + ks * 32 + quad * 8);

  const short oneb = 0x3F80;  // bf16 1.0
  bf16x8 vones = {oneb, oneb, oneb, oneb, oneb, oneb, oneb, oneb};

  floatx4 ctx[4], lacc;
#pragma unroll
  for (int nt = 0; nt < 4; nt++) {
    ctx[nt].x = 0.f; ctx[nt].y = 0.f; ctx[nt].z = 0.f; ctx[nt].w = 0.f;
  }
  lacc.x = 0.f; lacc.y = 0.f; lacc.z = 0.f; lacc.w = 0.f;

  for (int kt = 0; kt <= qt; kt++) {
    const int k0 = kt * 64;
    __syncthreads();
#pragma unroll
    for (int t = 0; t < 2; t++) {
      __builtin_amdgcn_global_load_lds(
          (const __attribute__((address_space(1))) void*)(gk[t] + (size_t)k0 * 2048),
          (__attribute__((address_space(3))) void*)lk[t], 16, 0, 0);
      __builtin_amdgcn_global_load_lds(
          (const __attribute__((address_space(1))) void*)(gv[t] + k0),
          (__attribute__((address_space(3))) void*)lv[t], 16, 0, 0);
    }
    __syncthreads();

    // ---- S = Q K^T ----
    floatx4 accS[4];
#pragma unroll
    for (int nt = 0; nt < 4; nt++) {
      accS[nt].x = 0.f; accS[nt].y = 0.f; accS[nt].z = 0.f; accS[nt].w = 0.f;
    }
#pragma unroll
    for (int ks = 0; ks < 2; ks++) {
      const int sq = ((quad + 4 * ks) ^ (tx & 7)) * 8;
      bf16x8 kf[4];
#pragma unroll
      for (int nt = 0; nt < 4; nt++)
        kf[nt] = *(const bf16x8*)&Ks[(nt * 16 + tx) * 64 + sq];
#pragma unroll
      for (int nt = 0; nt < 4; nt++)
        accS[nt] = __builtin_amdgcn_mfma_f32_16x16x32_bf16(qf[ks], kf[nt],
                                                           accS[nt], 0, 0, 0);
    }

    // ---- P = exp(S/8), mask, store swizzled ----
#pragma unroll
    for (int nt = 0; nt < 4; nt++) {
      const int jc = k0 + nt * 16 + tx;
      const bool ok = mask[b * S_ + jc] != 0;
      const int col = nt * 16 + tx;
#pragma unroll
      for (int r = 0; r < 4; r++) {
        const int qq = quad * 4 + r;
        const int qrow = q0 + w * 16 + qq;
        float p = exp2f(accS[nt][r] * 0.1803368801111244f);  // 0.125*log2(e)
        if (jc > qrow || !ok) p = 0.f;
        const int pc = ((((col >> 3) ^ (qq & 7)) << 3)) | (col & 7);
        Ps[(w * 16 + qq) * 64 + pc] =
            ((__hip_bfloat16_raw)__float2bfloat16(p)).x;
      }
    }

    // ---- ctx += P V ---- (same-wave Ps write->read, no barrier needed)
#pragma unroll
    for (int ks = 0; ks < 2; ks++) {
      const int sq = ((quad + 4 * ks) ^ (tx & 7)) * 8;
      const bf16x8 pf = *(const bf16x8*)&Ps[(w * 16 + tx) * 64 + sq];
      bf16x8 vf[4];
#pragma unroll
      for (int nt = 0; nt < 4; nt++)
        vf[nt] = *(const bf16x8*)&Vs[(nt * 16 + tx) * 64 + sq];
#pragma unroll
      for (int nt = 0; nt < 4; nt++)
        ctx[nt] = __builtin_amdgcn_mfma_f32_16x16x32_bf16(pf, vf[nt],
                                                          ctx[nt], 0, 0, 0);
      lacc = __builtin_amdgcn_mfma_f32_16x16x32_bf16(pf, vones, lacc, 0, 0, 0);
    }
  }

  const size_t obase = (size_t)b * S_ * D_ + (size_t)h * HD_;
  float rinv[4];
#pragma unroll
  for (int r = 0; r < 4; r++) rinv[r] = 1.0f / lacc[r];
#pragma unroll
  for (int nt = 0; nt < 4; nt++)
#pragma unroll
    for (int r = 0; r < 4; r++) {
      const int q = q0 + w * 16 + quad * 4 + r;
      O[obase + (size_t)q * D_ + nt * 16 + tx] =
          __float2bfloat16(ctx[nt][r] * rinv[r]);
    }
}

extern "C" void kernel_launch(void* const* d_in, const int* in_sizes, int n_in,
                              void* d_out, int out_size, void* d_ws, size_t ws_size,
                              hipStream_t stream) {
  const float* x = (const float*)d_in[0];
  const int* mask = (const int*)d_in[1];
  const float* wq = (const float*)d_in[2];
  const float* wk = (const float*)d_in[3];
  const float* wv = (const float*)d_in[4];
  const float* wo = (const float*)d_in[5];
  const float* bo = (const float*)d_in[6];
  const float* ln2s = (const float*)d_in[9];
  const float* ln2b = (const float*)d_in[10];
  const float* w1 = (const float*)d_in[11];
  const float* b1 = (const float*)d_in[12];
  const float* w2 = (const float*)d_in[13];
  const float* b2 = (const float*)d_in[14];
  float* out = (float*)d_out;

  const int M = B_ * S_;  // 4096
  char* ws = (char*)d_ws;
  const size_t MB = (size_t)1 << 20;
  bf16_t* qk = (bf16_t*)(ws);                  // [4096][2048] = 16 MB
  bf16_t* vT = (bf16_t*)(ws + 16 * MB);        // [1024][4096] = 8 MB
  bf16_t* ffn1 = (bf16_t*)(ws);                // step 6: qk/vT/Pa dead, 32 MB
  bf16_t* ctx = (bf16_t*)(ws + 32 * MB);       // 8 MB
  bf16_t* h = (bf16_t*)(ws + 40 * MB);         // 8 MB
  bf16_t* wqkv_t = (bf16_t*)(ws + 48 * MB);    // [3072,1024] = 6 MB
  bf16_t* wo_t = (bf16_t*)(ws + 54 * MB);      // [1024,1024] = 2 MB
  bf16_t* w1_t = (bf16_t*)(ws + 56 * MB);      // [4096,1024] = 8 MB
  bf16_t* w2_t = (bf16_t*)(ws + 64 * MB);      // [1024,4096] = 8 MB
  bf16_t* Pa = (bf16_t*)(ws);                  // step 4: qk/vT dead, 2x8MB
  bf16_t* Pf = (bf16_t*)(ws + 32 * MB);        // step 7: ctx/h/w*_t dead, 4x8MB
  const size_t slice = (size_t)M * D_;

  // 1. prep: h = LN1(x) + all weight transposes (one launch)
  prep_kernel<<<dim3(16384), 256, 0, stream>>>(x, (const float*)d_in[7],
                                               (const float*)d_in[8], h, wq, wk,
                                               wv, wo, w1, w2, wqkv_t, wo_t,
                                               w1_t, w2_t);

  // 2. merged: qk = h @ [wq|wk] (512 blocks) + vT = wv_t (x) h (256 blocks)
  qkv2_kernel<<<dim3(768), 256, 0, stream>>>(h, wqkv_t, qk, vT);

  // 3. ctx = softmax(causal(q k^T)/8) v -> bf16 (MFMA flash v2)
  fattn_kernel<<<dim3(S_ / 64, H_, B_), 256, 0, stream>>>(qk, vT, mask, ctx);

  // 4. attn-out split-K x2 (512 blocks, >=2/CU; PM=8,PN=1)
  mgemm_kernel<<<dim3(8 * 32 * 2), 256, 0, stream>>>(
      ctx, wo_t, nullptr, Pa, M, D_, D_, D_ / 2, /*Mt=*/4, /*Nt=*/8, /*PM=*/8, 4);

  // 5. out = x + Pa0 + Pa1 + bo ; h = LN2(out)   (fused)
  reduce2_ln_kernel<<<dim3(M), 256, 0, stream>>>(Pa, slice, x, bo, ln2s, ln2b,
                                                 out, h);

  // 6. ffn1 = gelu(h @ w1 + b1)  (256^2 tiles: 16x16 = 256 blocks)
  mgemm256_kernel<<<dim3(256), 512, 0, stream>>>(
      h, w1_t, b1, ffn1, M, 4 * D_, D_, D_, /*Mt=*/4, /*Nt=*/8, /*PM=*/4, 1);

  // 7. ffn2 split-K x4 (256^2 tiles: 16x4 x 4z = 256 blocks; PM=8,PN=1)
  mgemm256_kernel<<<dim3(256), 512, 0, stream>>>(
      ffn1, w2_t, nullptr, Pf, M, D_, 4 * D_, D_, /*Mt=*/2, /*Nt=*/4, /*PM=*/8, 4);

  // 8. out = out + sum(Pf) + b2
  reduce4_kernel<<<dim3((size_t)M * D_ / 1024), 256, 0, stream>>>(
      Pf, slice, b2, out, D_);
}

// Round 9
// 338.527 us; speedup vs baseline: 1.1370x; 1.0067x over previous
//
#include <hip/hip_runtime.h>
#include <hip/hip_bf16.h>
#include <math.h>

#define B_ 4
#define S_ 1024
#define D_ 1024
#define H_ 16
#define HD_ 64

typedef __hip_bfloat16 bf16_t;
typedef __attribute__((ext_vector_type(8))) short bf16x8;
typedef __attribute__((ext_vector_type(4))) float floatx4;

__device__ __forceinline__ float bf2f(ushort u) {
  return __uint_as_float((unsigned)u << 16);
}

// ---- prep: one launch = LN1 (4096 row-blocks) + all 6 weight transposes ----
__global__ __launch_bounds__(256) void prep_kernel(
    const float* __restrict__ x, const float* __restrict__ ln1s,
    const float* __restrict__ ln1b, bf16_t* __restrict__ h,
    const float* __restrict__ wq, const float* __restrict__ wk,
    const float* __restrict__ wv, const float* __restrict__ wo,
    const float* __restrict__ w1, const float* __restrict__ w2,
    bf16_t* __restrict__ wqkv_t, bf16_t* __restrict__ wo_t,
    bf16_t* __restrict__ w1_t, bf16_t* __restrict__ w2_t) {
  const int id = blockIdx.x;
  if (id < 4096) {  // ---- LayerNorm row ----
    const int row = id;
    float4 v = ((const float4*)(x + (size_t)row * D_))[threadIdx.x];
    float s = v.x + v.y + v.z + v.w;
    float ss = v.x * v.x + v.y * v.y + v.z * v.z + v.w * v.w;
#pragma unroll
    for (int off = 32; off > 0; off >>= 1) {
      s += __shfl_xor(s, off);
      ss += __shfl_xor(ss, off);
    }
    __shared__ float ls[4], lss[4], stats[2];
    const int wave = threadIdx.x >> 6, lane = threadIdx.x & 63;
    if (lane == 0) { ls[wave] = s; lss[wave] = ss; }
    __syncthreads();
    if (threadIdx.x == 0) {
      float t = ls[0] + ls[1] + ls[2] + ls[3];
      float tt = lss[0] + lss[1] + lss[2] + lss[3];
      float mean = t * (1.0f / D_);
      stats[0] = mean;
      stats[1] = rsqrtf(tt * (1.0f / D_) - mean * mean + 1e-5f);
    }
    __syncthreads();
    const float mean = stats[0], rstd = stats[1];
    float4 sc = ((const float4*)ln1s)[threadIdx.x];
    float4 sh = ((const float4*)ln1b)[threadIdx.x];
    bf16_t ob[4];
    ob[0] = __float2bfloat16(sc.x * (v.x - mean) * rstd + sh.x);
    ob[1] = __float2bfloat16(sc.y * (v.y - mean) * rstd + sh.y);
    ob[2] = __float2bfloat16(sc.z * (v.z - mean) * rstd + sh.z);
    ob[3] = __float2bfloat16(sc.w * (v.w - mean) * rstd + sh.w);
    *(ushort4*)(h + (size_t)row * D_ + threadIdx.x * 4) = *(ushort4*)ob;
    return;
  }
  const float* W;
  bf16_t* Wt;
  int K, N, n0, k0;
  if (id < 8192) {
    const int t = id - 4096, which = t >> 10, tile = t & 1023;
    n0 = (tile & 31) * 32;
    k0 = (tile >> 5) * 32;
    K = 1024; N = 1024;
    W = which == 0 ? wq : which == 1 ? wk : which == 2 ? wv : wo;
    Wt = which < 3 ? wqkv_t + (size_t)which * 1024 * 1024 : wo_t;
  } else if (id < 12288) {
    const int tile = id - 8192;
    n0 = (tile & 127) * 32;
    k0 = (tile >> 7) * 32;
    K = 1024; N = 4096;
    W = w1; Wt = w1_t;
  } else {
    const int tile = id - 12288;
    n0 = (tile & 31) * 32;
    k0 = (tile >> 5) * 32;
    K = 4096; N = 1024;
    W = w2; Wt = w2_t;
  }
  __shared__ float t[32][33];
  const int lx = threadIdx.x & 31, ly = threadIdx.x >> 5;  // 32 x 8
#pragma unroll
  for (int r = ly; r < 32; r += 8) t[r][lx] = W[(size_t)(k0 + r) * N + n0 + lx];
  __syncthreads();
#pragma unroll
  for (int r = ly; r < 32; r += 8)
    Wt[(size_t)(n0 + r) * K + k0 + lx] = __float2bfloat16(t[lx][r]);
}

// ------------- bf16 MFMA GEMM body: 128x128 tile, BK=64, XCD-clustered ------
// mode 0: C bf16 | 1: bias+gelu -> C bf16 | 4: bf16 partial + z*M*N (split-K)
// NOTE: keep grids >= 512 blocks (>=2 blocks/CU) — at 1 block/CU this 4-wave
// kernel has no co-resident block to hide the barrier drain (round-6: 93us).
__device__ __forceinline__ void mgemm_body(
    const bf16_t* __restrict__ A, const bf16_t* __restrict__ Bt,
    const float* __restrict__ bias, void* __restrict__ C, int M, int N, int K,
    int Kc, int Mt, int Nt, int PM, int mode, int flat, bf16_t* As,
    bf16_t* Bs) {
  const int tid = threadIdx.x;
  const int lane = tid & 63, w = tid >> 6;

  // --- XCD-cluster decode ---
  const int xcd = flat & 7;
  int t0 = flat >> 3;
  const int mb = xcd % PM, nb = xcd / PM;
  const int mt = mb * Mt + (t0 % Mt);
  t0 /= Mt;
  const int nt = nb * Nt + (t0 % Nt);
  const int z = t0 / Nt;
  const int m0 = mt * 128, n0 = nt * 128;
  const int kz0 = z * Kc;
  const int wm = (w >> 1) * 64, wn = (w & 1) * 64;

  floatx4 zero = {0.f, 0.f, 0.f, 0.f};
  floatx4 acc[4][4];
#pragma unroll
  for (int i = 0; i < 4; i++)
#pragma unroll
    for (int j = 0; j < 4; j++) acc[i][j] = zero;

  // staging: chunk c (1KB = 8 rows x 128B) handled by wave c&3, c = w+4t.
  const int ro8 = lane >> 3;                 // row within chunk
  const int g8 = ((lane & 7) ^ ro8) * 8;     // swizzled source col (elements)
  const bf16_t* ga[4];
  const bf16_t* gb[4];
  bf16_t* la[4];
  bf16_t* lb[4];
#pragma unroll
  for (int t = 0; t < 4; t++) {
    const int c = w + 4 * t;
    ga[t] = A + (size_t)(m0 + c * 8 + ro8) * K + g8;
    gb[t] = Bt + (size_t)(n0 + c * 8 + ro8) * K + g8;
    la[t] = &As[c * 512];
    lb[t] = &Bs[c * 512];
  }

  const int fr = lane & 15, quad = lane >> 4;

  for (int k0 = kz0; k0 < kz0 + Kc; k0 += 64) {
    __syncthreads();
#pragma unroll
    for (int t = 0; t < 4; t++) {
      __builtin_amdgcn_global_load_lds(
          (const __attribute__((address_space(1))) void*)(ga[t] + k0),
          (__attribute__((address_space(3))) void*)la[t], 16, 0, 0);
      __builtin_amdgcn_global_load_lds(
          (const __attribute__((address_space(1))) void*)(gb[t] + k0),
          (__attribute__((address_space(3))) void*)lb[t], 16, 0, 0);
    }
    __syncthreads();

#pragma unroll
    for (int ks = 0; ks < 2; ks++) {
      const int sq = ((quad + 4 * ks) ^ (fr & 7)) * 8;
      bf16x8 af[4], bfr[4];
#pragma unroll
      for (int i = 0; i < 4; i++) {
        af[i] = *(const bf16x8*)&As[(wm + i * 16 + fr) * 64 + sq];
        bfr[i] = *(const bf16x8*)&Bs[(wn + i * 16 + fr) * 64 + sq];
      }
#pragma unroll
      for (int i = 0; i < 4; i++)
#pragma unroll
        for (int j = 0; j < 4; j++)
          acc[i][j] = __builtin_amdgcn_mfma_f32_16x16x32_bf16(af[i], bfr[j],
                                                              acc[i][j], 0, 0, 0);
    }
  }

  // epilogue: C/D layout col=lane&15, row=quad*4+reg
  bf16_t* Pz = (mode == 4) ? ((bf16_t*)C + (size_t)z * M * N) : nullptr;
#pragma unroll
  for (int j = 0; j < 4; j++) {
    const int col = n0 + wn + j * 16 + fr;
    const float bj = bias ? bias[col] : 0.f;
#pragma unroll
    for (int i = 0; i < 4; i++) {
      const int rbase = m0 + wm + i * 16 + quad * 4;
#pragma unroll
      for (int r = 0; r < 4; r++) {
        const int row = rbase + r;
        float c = acc[i][j][r] + bj;
        if (mode == 1) {  // gelu(tanh) via fast sigmoid
          const float xg = c;
          const float t = 0.7978845608028654f * (xg + 0.044715f * xg * xg * xg);
          const float th = 2.0f / (1.0f + __expf(-2.0f * t)) - 1.0f;
          c = 0.5f * xg * (1.0f + th);
        }
        if (mode == 4) {
          Pz[(size_t)row * N + col] = __float2bfloat16(c);
        } else {
          ((bf16_t*)C)[(size_t)row * N + col] = __float2bfloat16(c);
        }
      }
    }
  }
}

__global__ __launch_bounds__(256) void mgemm_kernel(const bf16_t* __restrict__ A,
                                                    const bf16_t* __restrict__ Bt,
                                                    const float* __restrict__ bias,
                                                    void* __restrict__ C,
                                                    int M, int N, int K, int Kc,
                                                    int Mt, int Nt, int PM,
                                                    int mode) {
  __shared__ bf16_t As[128 * 64];
  __shared__ bf16_t Bs[128 * 64];
  mgemm_body(A, Bt, bias, C, M, N, K, Kc, Mt, Nt, PM, mode, blockIdx.x, As, Bs);
}

// ---- merged QKV: blocks 0-511 = qk GEMM, 512-767 = vT GEMM (one launch) ----
__global__ __launch_bounds__(256) void qkv2_kernel(const bf16_t* __restrict__ h,
                                                   const bf16_t* __restrict__ wqkv_t,
                                                   bf16_t* __restrict__ qk,
                                                   bf16_t* __restrict__ vT) {
  __shared__ bf16_t As[128 * 64];
  __shared__ bf16_t Bs[128 * 64];
  if (blockIdx.x < 512) {
    // qk = h @ [wq|wk]: M=4096, N=2048 (Mt=8, Nt=8, PM=4)
    mgemm_body(h, wqkv_t, nullptr, qk, 4096, 2048, 1024, 1024, 8, 8, 4, 0,
               blockIdx.x, As, Bs);
  } else {
    // vT = wv_t (x) h: M=1024, N=4096 (Mt=4, Nt=8, PM=2)
    mgemm_body(wqkv_t + (size_t)2 * 1024 * 1024, h, nullptr, vT, 1024, 4096,
               1024, 1024, 4, 8, 2, 0, blockIdx.x - 512, As, Bs);
  }
}

// ---- 256x256-tile GEMM: 4-phase dbuf, 2 counted waits per K-tile -----------
// (round-7 config, best measured: 51.2us. Round-8's all-at-phase-0 staging
// regressed to 55.2us — 8-load burst congests the VMEM queue. CLOSED.)
__global__ __launch_bounds__(512, 1) void mgemm256_kernel(
    const bf16_t* __restrict__ A, const bf16_t* __restrict__ Bt,
    const float* __restrict__ bias, void* __restrict__ C, int M, int N, int K,
    int Kc, int Mt, int Nt, int PM, int mode) {
  // [buf 0..1][ A[256][64] | B[256][64] ] = 2 * 64KB = 128 KB
  __shared__ bf16_t sm[65536];
  const int tid = threadIdx.x;
  const int lane = tid & 63, w = tid >> 6;

  const int flat = blockIdx.x;
  const int xcd = flat & 7;
  int t0 = flat >> 3;
  const int mb = xcd % PM, nb = xcd / PM;
  const int mt = mb * Mt + (t0 % Mt);
  t0 /= Mt;
  const int nt = nb * Nt + (t0 % Nt);
  const int z = t0 / Nt;
  const int m0 = mt * 256, n0 = nt * 256;
  const int kz0 = z * Kc;
  const int wr = (w >> 2) & 1, wc = w & 3;

  floatx4 zero = {0.f, 0.f, 0.f, 0.f};
  floatx4 acc[8][4];
#pragma unroll
  for (int i = 0; i < 8; i++)
#pragma unroll
    for (int j = 0; j < 4; j++) acc[i][j] = zero;

  const int r_t = tid >> 3;                                  // 0..63
  const int g8s = (((tid & 7) ^ (r_t & 7)) << 3);            // src col (elems)
  const int fr = lane & 15, quad = lane >> 4;

  // unit: 0 = B rows 0-127, 1 = B rows 128-255, 2 = A rows 0-127, 3 = A 128-255
  auto STAGE = [&](int nbuf, int unit, int kk) {
    const bf16_t* src0 =
        (unit < 2) ? Bt + (size_t)(n0 + (unit & 1) * 128 + r_t) * K + g8s + kk
                   : A + (size_t)(m0 + (unit & 1) * 128 + r_t) * K + g8s + kk;
    bf16_t* d0 = &sm[nbuf * 32768 + (unit < 2 ? 16384 : 0) + (unit & 1) * 8192 +
                     tid * 8];
#pragma unroll
    for (int l = 0; l < 2; ++l) {
      __builtin_amdgcn_global_load_lds(
          (const __attribute__((address_space(1))) void*)(src0 +
                                                          (size_t)l * 64 * K),
          (__attribute__((address_space(3))) void*)(d0 + l * 4096), 16, 0, 0);
    }
  };

  const int ntk = Kc >> 6;  // BK = 64

  // prologue: full tile 0 into buf 0 (units B0,B1,A0,A1)
  STAGE(0, 0, kz0); STAGE(0, 1, kz0); STAGE(0, 2, kz0); STAGE(0, 3, kz0);
  asm volatile("s_waitcnt vmcnt(2)" ::: "memory");  // B0,B1,A0 landed
  __builtin_amdgcn_s_barrier();

#define DO_PHASE(KS, MH, UNIT, WAIT)                                           \
  {                                                                            \
    const int sq = (((quad + 4 * (KS)) ^ (fr & 7)) << 3);                      \
    bf16x8 af[4];                                                              \
    _Pragma("unroll") for (int i = 0; i < 4; ++i) af[i] =                      \
        *(const bf16x8*)&sm[bo + ((MH)*128 + wr * 64 + i * 16 + fr) * 64 + sq];\
    if ((MH) == 0) {                                                           \
      _Pragma("unroll") for (int j = 0; j < 4; ++j) bfr[j] =                   \
          *(const bf16x8*)&sm[bo + 16384 + (wc * 64 + j * 16 + fr) * 64 + sq]; \
    }                                                                          \
    if (pre) STAGE(nbuf, (UNIT), kn);                                          \
    __builtin_amdgcn_s_barrier();                                              \
    asm volatile("s_waitcnt lgkmcnt(0)" ::: "memory");                         \
    __builtin_amdgcn_sched_barrier(0);                                         \
    __builtin_amdgcn_s_setprio(1);                                             \
    _Pragma("unroll") for (int i = 0; i < 4; ++i)                              \
        _Pragma("unroll") for (int j = 0; j < 4; ++j) acc[(MH)*4 + i][j] =     \
            __builtin_amdgcn_mfma_f32_16x16x32_bf16(af[i], bfr[j],             \
                                                    acc[(MH)*4 + i][j], 0, 0,  \
                                                    0);                        \
    __builtin_amdgcn_s_setprio(0);                                             \
    if (WAIT) {                                                                \
      if (pre) {                                                               \
        asm volatile("s_waitcnt vmcnt(2)" ::: "memory");                       \
      } else {                                                                 \
        asm volatile("s_waitcnt vmcnt(0)" ::: "memory");                       \
      }                                                                        \
    }                                                                          \
    __builtin_amdgcn_s_barrier();                                              \
  }

  for (int t = 0; t < ntk; ++t) {
    const int bo = (t & 1) * 32768;
    const int nbuf = (t + 1) & 1;
    const int kn = kz0 + (t + 1) * 64;
    const bool pre = (t + 1 < ntk);
    bf16x8 bfr[4];
    DO_PHASE(0, 0, 0, 1)  // ks0, mh0; stage B-h0(t+1); wait A1(t)
    DO_PHASE(0, 1, 1, 0)  // ks0, mh1; stage B-h1(t+1)
    DO_PHASE(1, 0, 2, 0)  // ks1, mh0; stage A-h0(t+1)
    DO_PHASE(1, 1, 3, 1)  // ks1, mh1; stage A-h1(t+1); wait B0,B1,A0(t+1)
  }
#undef DO_PHASE

  // ---- epilogue: per-wave 8KB LDS bounce -> 16B coalesced stores ----
  __syncthreads();
  bf16_t* sl = sm + w * 4096;  // 64 x 64 slice per wave
  bf16_t* Pz = (mode == 4) ? ((bf16_t*)C + (size_t)z * M * N) : (bf16_t*)C;
  float bj[4];
#pragma unroll
  for (int j = 0; j < 4; ++j)
    bj[j] = bias ? bias[n0 + wc * 64 + j * 16 + fr] : 0.f;
#pragma unroll
  for (int mh = 0; mh < 2; ++mh) {
    if (mh) {  // own-slice reuse: ensure pass-0 LDS reads fully drained
      asm volatile("s_waitcnt lgkmcnt(0)" ::: "memory");
      __builtin_amdgcn_sched_barrier(0);
    }
#pragma unroll
    for (int i = 0; i < 4; ++i)
#pragma unroll
      for (int j = 0; j < 4; ++j)
#pragma unroll
        for (int r = 0; r < 4; ++r) {
          const int rl = i * 16 + quad * 4 + r, cl = j * 16 + fr;
          float c = acc[mh * 4 + i][j][r] + bj[j];
          if (mode == 1) {  // gelu(tanh) via fast sigmoid
            const float xg = c;
            const float t2 =
                0.7978845608028654f * (xg + 0.044715f * xg * xg * xg);
            const float th = 2.0f / (1.0f + __expf(-2.0f * t2)) - 1.0f;
            c = 0.5f * xg * (1.0f + th);
          }
          const int cg = (cl >> 3) ^ (rl & 7);
          sl[rl * 64 + cg * 8 + (cl & 7)] = __float2bfloat16(c);
        }
#pragma unroll
    for (int it = 0; it < 8; ++it) {
      const int gi = it * 64 + lane;
      const int rl = gi >> 3, g = gi & 7;
      const bf16x8 vv = *(const bf16x8*)&sl[rl * 64 + ((g ^ (rl & 7)) * 8)];
      *(bf16x8*)&Pz[(size_t)(m0 + mh * 128 + wr * 64 + rl) * N + n0 + wc * 64 +
                    g * 8] = vv;
    }
  }
}

// --- fused: out = x + P0 + P1 + bias ; h = LN2(out). One block per row. -----
__global__ __launch_bounds__(256) void reduce2_ln_kernel(
    const bf16_t* __restrict__ P, size_t slice, const float* __restrict__ x,
    const float* __restrict__ bias, const float* __restrict__ scale,
    const float* __restrict__ shift, float* __restrict__ out,
    bf16_t* __restrict__ h) {
  const int row = blockIdx.x;
  const size_t e = (size_t)row * D_ + threadIdx.x * 4;
  const float4 xv = *(const float4*)(x + e);
  const ushort4 p0 = *(const ushort4*)((const ushort*)P + e);
  const ushort4 p1 = *(const ushort4*)((const ushort*)P + slice + e);
  const float4 bb = *(const float4*)(bias + threadIdx.x * 4);
  float4 v;
  v.x = xv.x + bf2f(p0.x) + bf2f(p1.x) + bb.x;
  v.y = xv.y + bf2f(p0.y) + bf2f(p1.y) + bb.y;
  v.z = xv.z + bf2f(p0.z) + bf2f(p1.z) + bb.z;
  v.w = xv.w + bf2f(p0.w) + bf2f(p1.w) + bb.w;
  *(float4*)(out + e) = v;

  float s = v.x + v.y + v.z + v.w;
  float ss = v.x * v.x + v.y * v.y + v.z * v.z + v.w * v.w;
#pragma unroll
  for (int off = 32; off > 0; off >>= 1) {
    s += __shfl_xor(s, off);
    ss += __shfl_xor(ss, off);
  }
  __shared__ float ls[4], lss[4], stats[2];
  const int wave = threadIdx.x >> 6, lane = threadIdx.x & 63;
  if (lane == 0) { ls[wave] = s; lss[wave] = ss; }
  __syncthreads();
  if (threadIdx.x == 0) {
    float t = ls[0] + ls[1] + ls[2] + ls[3];
    float tt = lss[0] + lss[1] + lss[2] + lss[3];
    float mean = t * (1.0f / D_);
    stats[0] = mean;
    stats[1] = rsqrtf(tt * (1.0f / D_) - mean * mean + 1e-5f);
  }
  __syncthreads();
  const float mean = stats[0], rstd = stats[1];
  const float4 sc = *(const float4*)(scale + threadIdx.x * 4);
  const float4 sh = *(const float4*)(shift + threadIdx.x * 4);
  bf16_t ob[4];
  ob[0] = __float2bfloat16(sc.x * (v.x - mean) * rstd + sh.x);
  ob[1] = __float2bfloat16(sc.y * (v.y - mean) * rstd + sh.y);
  ob[2] = __float2bfloat16(sc.z * (v.z - mean) * rstd + sh.z);
  ob[3] = __float2bfloat16(sc.w * (v.w - mean) * rstd + sh.w);
  *(ushort4*)(h + e) = *(ushort4*)ob;
}

// --- split-K x4 reduce: out = out + P0+P1+P2+P3 + bias (P bf16) -------------
__global__ __launch_bounds__(256) void reduce4_kernel(const bf16_t* __restrict__ P,
                                                      size_t slice,
                                                      const float* __restrict__ bias,
                                                      float* __restrict__ out,
                                                      int N) {
  const size_t e = ((size_t)blockIdx.x * 256 + threadIdx.x) * 4;
  const ushort* Pu = (const ushort*)P;
  const ushort4 p0 = *(const ushort4*)(Pu + e);
  const ushort4 p1 = *(const ushort4*)(Pu + slice + e);
  const ushort4 p2 = *(const ushort4*)(Pu + 2 * slice + e);
  const ushort4 p3 = *(const ushort4*)(Pu + 3 * slice + e);
  const float4 r = *(const float4*)(out + e);
  const float4 bb = *(const float4*)(bias + (int)(e % N));
  float4 o;
  o.x = r.x + bb.x + bf2f(p0.x) + bf2f(p1.x) + bf2f(p2.x) + bf2f(p3.x);
  o.y = r.y + bb.y + bf2f(p0.y) + bf2f(p1.y) + bf2f(p2.y) + bf2f(p3.y);
  o.z = r.z + bb.z + bf2f(p0.z) + bf2f(p1.z) + bf2f(p2.z) + bf2f(p3.z);
  o.w = r.w + bb.w + bf2f(p0.w) + bf2f(p1.w) + bf2f(p2.w) + bf2f(p3.w);
  *(float4*)(out + e) = o;
}

// ------------- MFMA flash attention v3: QBLK=128 (fixed-max softmax) --------
// QK: [4096][2048] bf16, Q at col h*64, K at col 1024+h*64.
// VT: [1024][4096] bf16, row = h*64+d, col = b*1024+s  (V pre-transposed).
// 512 blocks (2/CU), 4 waves x 32 q-rows. Each K/V tile load amortized over
// 2x MFMA work vs v2: tile-loads per (b,h) 136 -> 72, barriers likewise.
__global__ __launch_bounds__(256) void fattn_kernel(const bf16_t* __restrict__ QK,
                                                    const bf16_t* __restrict__ VT,
                                                    const int* __restrict__ mask,
                                                    bf16_t* __restrict__ O) {
  const int qb = gridDim.x - 1 - blockIdx.x;  // heavy blocks first
  const int h = blockIdx.y, b = blockIdx.z;
  const int tid = threadIdx.x;
  const int lane = tid & 63, w = tid >> 6;
  const int tx = lane & 15, quad = lane >> 4;
  const int q0 = qb * 128;

  __shared__ bf16_t Ks[64 * 64];   // K-tile [j][d], swizzled granules
  __shared__ bf16_t Vs[64 * 64];   // V^T-tile [d][j], swizzled granules
  __shared__ ushort Ps[128 * 64];  // P [q][j], swizzled granules

  // staging: chunk c (8 rows x 128B), c = w + 4t
  const int ro8 = lane >> 3;
  const int g8 = ((lane & 7) ^ ro8) * 8;  // swizzled source granule
  const bf16_t* gk[2];
  const bf16_t* gv[2];
  bf16_t* lk[2];
  bf16_t* lv[2];
#pragma unroll
  for (int t = 0; t < 2; t++) {
    const int c = w + 4 * t;
    gk[t] = QK + (size_t)((size_t)b * S_ + c * 8 + ro8) * 2048 + 1024 + h * HD_ + g8;
    gv[t] = VT + (size_t)(h * HD_ + c * 8 + ro8) * 4096 + (size_t)b * S_ + g8;
    lk[t] = &Ks[c * 512];
    lv[t] = &Vs[c * 512];
  }

  // Q fragments: wave w owns rows q0 + w*32 + m*16 + tx, m in {0,1}
  bf16x8 qf[2][2];
#pragma unroll
  for (int m = 0; m < 2; m++)
#pragma unroll
    for (int ks = 0; ks < 2; ks++)
      qf[m][ks] = *(const bf16x8*)(QK +
                                   (size_t)((size_t)b * S_ + q0 + w * 32 +
                                            m * 16 + tx) * 2048 +
                                   h * HD_ + ks * 32 + quad * 8);

  const short oneb = 0x3F80;  // bf16 1.0
  bf16x8 vones = {oneb, oneb, oneb, oneb, oneb, oneb, oneb, oneb};

  floatx4 ctx[2][4], lacc[2];
#pragma unroll
  for (int m = 0; m < 2; m++) {
#pragma unroll
    for (int nt = 0; nt < 4; nt++) {
      ctx[m][nt].x = 0.f; ctx[m][nt].y = 0.f;
      ctx[m][nt].z = 0.f; ctx[m][nt].w = 0.f;
    }
    lacc[m].x = 0.f; lacc[m].y = 0.f; lacc[m].z = 0.f; lacc[m].w = 0.f;
  }

  const int ktmax = 2 * qb + 1;
  for (int kt = 0; kt <= ktmax; kt++) {
    const int k0 = kt * 64;
    __syncthreads();
#pragma unroll
    for (int t = 0; t < 2; t++) {
      __builtin_amdgcn_global_load_lds(
          (const __attribute__((address_space(1))) void*)(gk[t] + (size_t)k0 * 2048),
          (__attribute__((address_space(3))) void*)lk[t], 16, 0, 0);
      __builtin_amdgcn_global_load_lds(
          (const __attribute__((address_space(1))) void*)(gv[t] + k0),
          (__attribute__((address_space(3))) void*)lv[t], 16, 0, 0);
    }
    __syncthreads();

    // ---- S = Q K^T (both 16-row fragments share kf loads) ----
    floatx4 accS[2][4];
#pragma unroll
    for (int m = 0; m < 2; m++)
#pragma unroll
      for (int nt = 0; nt < 4; nt++) {
        accS[m][nt].x = 0.f; accS[m][nt].y = 0.f;
        accS[m][nt].z = 0.f; accS[m][nt].w = 0.f;
      }
#pragma unroll
    for (int ks = 0; ks < 2; ks++) {
      const int sq = ((quad + 4 * ks) ^ (tx & 7)) * 8;
      bf16x8 kf[4];
#pragma unroll
      for (int nt = 0; nt < 4; nt++)
        kf[nt] = *(const bf16x8*)&Ks[(nt * 16 + tx) * 64 + sq];
#pragma unroll
      for (int m = 0; m < 2; m++)
#pragma unroll
        for (int nt = 0; nt < 4; nt++)
          accS[m][nt] = __builtin_amdgcn_mfma_f32_16x16x32_bf16(
              qf[m][ks], kf[nt], accS[m][nt], 0, 0, 0);
    }

    // ---- P = exp(S/8), mask, store swizzled ----
#pragma unroll
    for (int nt = 0; nt < 4; nt++) {
      const int jc = k0 + nt * 16 + tx;
      const bool ok = mask[b * S_ + jc] != 0;
      const int col = nt * 16 + tx;
#pragma unroll
      for (int m = 0; m < 2; m++)
#pragma unroll
        for (int r = 0; r < 4; r++) {
          const int qq = quad * 4 + r;
          const int qrow = q0 + w * 32 + m * 16 + qq;
          float p = exp2f(accS[m][nt][r] * 0.1803368801111244f);  // .125*log2e
          if (jc > qrow || !ok) p = 0.f;
          const int pc = ((((col >> 3) ^ (qq & 7)) << 3)) | (col & 7);
          Ps[(w * 32 + m * 16 + qq) * 64 + pc] =
              ((__hip_bfloat16_raw)__float2bfloat16(p)).x;
        }
    }

    // ---- ctx += P V ---- (same-wave Ps write->read; vf shared across m)
#pragma unroll
    for (int ks = 0; ks < 2; ks++) {
      const int sq = ((quad + 4 * ks) ^ (tx & 7)) * 8;
      bf16x8 vf[4];
#pragma unroll
      for (int nt = 0; nt < 4; nt++)
        vf[nt] = *(const bf16x8*)&Vs[(nt * 16 + tx) * 64 + sq];
#pragma unroll
      for (int m = 0; m < 2; m++) {
        const bf16x8 pf =
            *(const bf16x8*)&Ps[(w * 32 + m * 16 + tx) * 64 + sq];
#pragma unroll
        for (int nt = 0; nt < 4; nt++)
          ctx[m][nt] = __builtin_amdgcn_mfma_f32_16x16x32_bf16(pf, vf[nt],
                                                               ctx[m][nt], 0,
                                                               0, 0);
        lacc[m] = __builtin_amdgcn_mfma_f32_16x16x32_bf16(pf, vones, lacc[m],
                                                          0, 0, 0);
      }
    }
  }

  const size_t obase = (size_t)b * S_ * D_ + (size_t)h * HD_;
#pragma unroll
  for (int m = 0; m < 2; m++) {
    float rinv[4];
#pragma unroll
    for (int r = 0; r < 4; r++) rinv[r] = 1.0f / lacc[m][r];
#pragma unroll
    for (int nt = 0; nt < 4; nt++)
#pragma unroll
      for (int r = 0; r < 4; r++) {
        const int q = q0 + w * 32 + m * 16 + quad * 4 + r;
        O[obase + (size_t)q * D_ + nt * 16 + tx] =
            __float2bfloat16(ctx[m][nt][r] * rinv[r]);
      }
  }
}

extern "C" void kernel_launch(void* const* d_in, const int* in_sizes, int n_in,
                              void* d_out, int out_size, void* d_ws, size_t ws_size,
                              hipStream_t stream) {
  const float* x = (const float*)d_in[0];
  const int* mask = (const int*)d_in[1];
  const float* wq = (const float*)d_in[2];
  const float* wk = (const float*)d_in[3];
  const float* wv = (const float*)d_in[4];
  const float* wo = (const float*)d_in[5];
  const float* bo = (const float*)d_in[6];
  const float* ln2s = (const float*)d_in[9];
  const float* ln2b = (const float*)d_in[10];
  const float* w1 = (const float*)d_in[11];
  const float* b1 = (const float*)d_in[12];
  const float* w2 = (const float*)d_in[13];
  const float* b2 = (const float*)d_in[14];
  float* out = (float*)d_out;

  const int M = B_ * S_;  // 4096
  char* ws = (char*)d_ws;
  const size_t MB = (size_t)1 << 20;
  bf16_t* qk = (bf16_t*)(ws);                  // [4096][2048] = 16 MB
  bf16_t* vT = (bf16_t*)(ws + 16 * MB);        // [1024][4096] = 8 MB
  bf16_t* ffn1 = (bf16_t*)(ws);                // step 6: qk/vT/Pa dead, 32 MB
  bf16_t* ctx = (bf16_t*)(ws + 32 * MB);       // 8 MB
  bf16_t* h = (bf16_t*)(ws + 40 * MB);         // 8 MB
  bf16_t* wqkv_t = (bf16_t*)(ws + 48 * MB);    // [3072,1024] = 6 MB
  bf16_t* wo_t = (bf16_t*)(ws + 54 * MB);      // [1024,1024] = 2 MB
  bf16_t* w1_t = (bf16_t*)(ws + 56 * MB);      // [4096,1024] = 8 MB
  bf16_t* w2_t = (bf16_t*)(ws + 64 * MB);      // [1024,4096] = 8 MB
  bf16_t* Pa = (bf16_t*)(ws);                  // step 4: qk/vT dead, 2x8MB
  bf16_t* Pf = (bf16_t*)(ws + 32 * MB);        // step 7: ctx/h/w*_t dead, 4x8MB
  const size_t slice = (size_t)M * D_;

  // 1. prep: h = LN1(x) + all weight transposes (one launch)
  prep_kernel<<<dim3(16384), 256, 0, stream>>>(x, (const float*)d_in[7],
                                               (const float*)d_in[8], h, wq, wk,
                                               wv, wo, w1, w2, wqkv_t, wo_t,
                                               w1_t, w2_t);

  // 2. merged: qk = h @ [wq|wk] (512 blocks) + vT = wv_t (x) h (256 blocks)
  qkv2_kernel<<<dim3(768), 256, 0, stream>>>(h, wqkv_t, qk, vT);

  // 3. ctx = softmax(causal(q k^T)/8) v -> bf16 (flash v3, QBLK=128)
  fattn_kernel<<<dim3(S_ / 128, H_, B_), 256, 0, stream>>>(qk, vT, mask, ctx);

  // 4. attn-out split-K x2 (512 blocks, >=2/CU; PM=8,PN=1)
  mgemm_kernel<<<dim3(8 * 32 * 2), 256, 0, stream>>>(
      ctx, wo_t, nullptr, Pa, M, D_, D_, D_ / 2, /*Mt=*/4, /*Nt=*/8, /*PM=*/8, 4);

  // 5. out = x + Pa0 + Pa1 + bo ; h = LN2(out)   (fused)
  reduce2_ln_kernel<<<dim3(M), 256, 0, stream>>>(Pa, slice, x, bo, ln2s, ln2b,
                                                 out, h);

  // 6. ffn1 = gelu(h @ w1 + b1)  (256^2 tiles: 16x16 = 256 blocks)
  mgemm256_kernel<<<dim3(256), 512, 0, stream>>>(
      h, w1_t, b1, ffn1, M, 4 * D_, D_, D_, /*Mt=*/4, /*Nt=*/8, /*PM=*/4, 1);

  // 7. ffn2 split-K x4 (256^2 tiles: 16x4 x 4z = 256 blocks; PM=8,PN=1)
  mgemm256_kernel<<<dim3(256), 512, 0, stream>>>(
      ffn1, w2_t, nullptr, Pf, M, D_, 4 * D_, D_, /*Mt=*/2, /*Nt=*/4, /*PM=*/8, 4);

  // 8. out = out + sum(Pf) + b2
  reduce4_kernel<<<dim3((size_t)M * D_ / 1024), 256, 0, stream>>>(
      Pf, slice, b2, out, D_);
}